// Round 8
// baseline (352.072 us; speedup 1.0000x reference)
//
#include <hip/hip_runtime.h>
#include <float.h>
#include <math.h>

// Problem constants: B=32, NF=64, FD=64, ND=256, C=8, K=6, L=2, scale=1/8.

typedef short bf8t __attribute__((ext_vector_type(8)));   // 8 bf16 in 4 VGPRs
typedef float f4t __attribute__((ext_vector_type(4)));

static __device__ __forceinline__ unsigned short f2bf(float x) {
  union { float f; unsigned u; } v; v.f = x;
  unsigned r = (v.u + 0x7FFFu + ((v.u >> 16) & 1u)) >> 16;
  return (unsigned short)r;
}
static __device__ __forceinline__ float bf2f(unsigned short s) {
  union { unsigned u; float f; } v; v.u = ((unsigned)s) << 16; return v.f;
}
static __device__ __forceinline__ float bf2f_lo(unsigned u) {
  union { unsigned u; float f; } v; v.u = u << 16; return v.f;
}
static __device__ __forceinline__ float bf2f_hi(unsigned u) {
  union { unsigned u; float f; } v; v.u = u & 0xFFFF0000u; return v.f;
}
// 2 packed elems of the 3-term split dot: qh*(kh+kl) + ql*kh
static __device__ __forceinline__ float dot3_pair(unsigned uqh, unsigned uql,
                                                  unsigned ukh, unsigned ukl) {
  float s = bf2f_lo(uqh) * (bf2f_lo(ukh) + bf2f_lo(ukl)) + bf2f_lo(uql) * bf2f_lo(ukh);
  s += bf2f_hi(uqh) * (bf2f_hi(ukh) + bf2f_hi(ukl)) + bf2f_hi(uql) * bf2f_hi(ukh);
  return s;
}
// split 8 fp32 into hi/lo bf16 fragments
static __device__ __forceinline__ void split8(const float* __restrict__ p,
                                              bf8t* hi, bf8t* lo) {
  float4 v0 = *(const float4*)(p);
  float4 v1 = *(const float4*)(p + 4);
  float v[8] = {v0.x, v0.y, v0.z, v0.w, v1.x, v1.y, v1.z, v1.w};
#pragma unroll
  for (int j = 0; j < 8; j++) {
    unsigned short h = f2bf(v[j]);
    (*hi)[j] = (short)h;
    (*lo)[j] = (short)f2bf(v[j] - bf2f(h));
  }
}

#define SPAD 68   // LDS row stride for speclip (16B-aligned rows)

// ---------------------------------------------------------------------------
// MFMA 64x64 row-row matmul on LDS (stride SPAD), bf16 3-term split.
// ---------------------------------------------------------------------------
static __device__ __forceinline__ void mm_mfma(
    const float* __restrict__ A, const float* __restrict__ B,
    float* __restrict__ C, int t, float scale, int addI, int transposeStore) {
  int wv = t >> 6, l = t & 63;
  int m16 = l & 15, quad = l >> 4;
  bf8t ah[2], al[2];
  const float* ap = A + (size_t)(16 * wv + m16) * SPAD + quad * 8;
  split8(ap, &ah[0], &al[0]);
  split8(ap + 32, &ah[1], &al[1]);
  f4t acc[4];
#pragma unroll
  for (int ct = 0; ct < 4; ct++) {
    bf8t bh[2], bl[2];
    const float* bp = B + (size_t)(ct * 16 + m16) * SPAD + quad * 8;
    split8(bp, &bh[0], &bl[0]);
    split8(bp + 32, &bh[1], &bl[1]);
    f4t a = (f4t){0.f, 0.f, 0.f, 0.f};
    a = __builtin_amdgcn_mfma_f32_16x16x32_bf16(al[0], bh[0], a, 0, 0, 0);
    a = __builtin_amdgcn_mfma_f32_16x16x32_bf16(ah[0], bl[0], a, 0, 0, 0);
    a = __builtin_amdgcn_mfma_f32_16x16x32_bf16(ah[0], bh[0], a, 0, 0, 0);
    a = __builtin_amdgcn_mfma_f32_16x16x32_bf16(al[1], bh[1], a, 0, 0, 0);
    a = __builtin_amdgcn_mfma_f32_16x16x32_bf16(ah[1], bl[1], a, 0, 0, 0);
    a = __builtin_amdgcn_mfma_f32_16x16x32_bf16(ah[1], bh[1], a, 0, 0, 0);
    acc[ct] = a;
  }
#pragma unroll
  for (int ct = 0; ct < 4; ct++)
#pragma unroll
    for (int j = 0; j < 4; j++) {
      int i0 = 16 * wv + quad * 4 + j;
      int j0 = ct * 16 + m16;
      float v = acc[ct][j] * scale + ((addI && i0 == j0) ? 1.0f : 0.0f);
      if (transposeStore) C[(size_t)j0 * SPAD + i0] = v;
      else C[(size_t)i0 * SPAD + j0] = v;
    }
}

// Squaring with max-normalization: C = (A A^T) / maxabs (A symmetric -> A^2).
static __device__ __forceinline__ void mm_sq_norm(
    const float* __restrict__ A, float* __restrict__ C, int t,
    float* __restrict__ redm) {
  int wv = t >> 6, l = t & 63;
  int m16 = l & 15, quad = l >> 4;
  bf8t ah[2], al[2];
  const float* ap = A + (size_t)(16 * wv + m16) * SPAD + quad * 8;
  split8(ap, &ah[0], &al[0]);
  split8(ap + 32, &ah[1], &al[1]);
  f4t acc[4];
#pragma unroll
  for (int ct = 0; ct < 4; ct++) {
    bf8t bh[2], bl[2];
    const float* bp = A + (size_t)(ct * 16 + m16) * SPAD + quad * 8;
    split8(bp, &bh[0], &bl[0]);
    split8(bp + 32, &bh[1], &bl[1]);
    f4t a = (f4t){0.f, 0.f, 0.f, 0.f};
    a = __builtin_amdgcn_mfma_f32_16x16x32_bf16(al[0], bh[0], a, 0, 0, 0);
    a = __builtin_amdgcn_mfma_f32_16x16x32_bf16(ah[0], bl[0], a, 0, 0, 0);
    a = __builtin_amdgcn_mfma_f32_16x16x32_bf16(ah[0], bh[0], a, 0, 0, 0);
    a = __builtin_amdgcn_mfma_f32_16x16x32_bf16(al[1], bh[1], a, 0, 0, 0);
    a = __builtin_amdgcn_mfma_f32_16x16x32_bf16(ah[1], bl[1], a, 0, 0, 0);
    a = __builtin_amdgcn_mfma_f32_16x16x32_bf16(ah[1], bh[1], a, 0, 0, 0);
    acc[ct] = a;
  }
  float mx = 0.f;
#pragma unroll
  for (int ct = 0; ct < 4; ct++)
#pragma unroll
    for (int j = 0; j < 4; j++) mx = fmaxf(mx, fabsf(acc[ct][j]));
#pragma unroll
  for (int m = 1; m < 64; m <<= 1) mx = fmaxf(mx, __shfl_xor(mx, m, 64));
  if (l == 0) redm[wv] = mx;
  __syncthreads();
  float gmx = fmaxf(fmaxf(redm[0], redm[1]), fmaxf(redm[2], redm[3]));
  float sc = 1.0f / fmaxf(gmx, 1e-30f);
#pragma unroll
  for (int ct = 0; ct < 4; ct++)
#pragma unroll
    for (int j = 0; j < 4; j++)
      C[(size_t)(16 * wv + quad * 4 + j) * SPAD + ct * 16 + m16] = acc[ct][j] * sc;
}

// Gram via MFMA: G = Ag * Ag^T (Ag 64 x ncols row-major global), staged in S.
static __device__ __forceinline__ void gram_mfma(
    const float* __restrict__ Ag, int ncols, float* __restrict__ S,
    float* __restrict__ G, int t) {
  int wv = t >> 6, l = t & 63;
  int m16 = l & 15, quad = l >> 4;
  f4t acc[4];
#pragma unroll
  for (int ct = 0; ct < 4; ct++) acc[ct] = (f4t){0.f, 0.f, 0.f, 0.f};
  for (int cc = 0; cc < ncols; cc += 64) {
    if (cc) __syncthreads();
    for (int i = t; i < 1024; i += 256) {
      int r = i >> 4, qq = i & 15;
      float4 v = *(const float4*)(Ag + (size_t)r * ncols + cc + 4 * qq);
      *(float4*)(S + (size_t)r * SPAD + 4 * qq) = v;
    }
    __syncthreads();
    bf8t ah[2], al[2];
    const float* ap = S + (size_t)(16 * wv + m16) * SPAD + quad * 8;
    split8(ap, &ah[0], &al[0]);
    split8(ap + 32, &ah[1], &al[1]);
#pragma unroll
    for (int ct = 0; ct < 4; ct++) {
      bf8t bh[2], bl[2];
      const float* bp = S + (size_t)(ct * 16 + m16) * SPAD + quad * 8;
      split8(bp, &bh[0], &bl[0]);
      split8(bp + 32, &bh[1], &bl[1]);
      f4t a = acc[ct];
      a = __builtin_amdgcn_mfma_f32_16x16x32_bf16(al[0], bh[0], a, 0, 0, 0);
      a = __builtin_amdgcn_mfma_f32_16x16x32_bf16(ah[0], bl[0], a, 0, 0, 0);
      a = __builtin_amdgcn_mfma_f32_16x16x32_bf16(ah[0], bh[0], a, 0, 0, 0);
      a = __builtin_amdgcn_mfma_f32_16x16x32_bf16(al[1], bh[1], a, 0, 0, 0);
      a = __builtin_amdgcn_mfma_f32_16x16x32_bf16(ah[1], bl[1], a, 0, 0, 0);
      a = __builtin_amdgcn_mfma_f32_16x16x32_bf16(ah[1], bh[1], a, 0, 0, 0);
      acc[ct] = a;
    }
  }
  __syncthreads();
#pragma unroll
  for (int ct = 0; ct < 4; ct++)
#pragma unroll
    for (int j = 0; j < 4; j++)
      G[(size_t)(16 * wv + quad * 4 + j) * SPAD + ct * 16 + m16] = acc[ct][j];
}

// Single-wave power iteration (4-partial ILP) + Rayleigh on Gm (t < 64).
static __device__ __forceinline__ float power_rayleigh(
    const float* __restrict__ G4m, const float* __restrict__ Gm, int iters, int i) {
  float row[64];
#pragma unroll
  for (int j = 0; j < 16; j++)
    *(float4*)(row + 4 * j) = *(const float4*)(G4m + (size_t)i * SPAD + 4 * j);
  float v = 1.0f + 0.3f * sinf(7.0f * (float)(i + 1));
  for (int it = 0; it < iters; it++) {
    float u0 = 0.f, u1 = 0.f, u2 = 0.f, u3 = 0.f;
#pragma unroll
    for (int j = 0; j < 16; j++) {
      u0 += row[4 * j + 0] * __shfl(v, 4 * j + 0, 64);
      u1 += row[4 * j + 1] * __shfl(v, 4 * j + 1, 64);
      u2 += row[4 * j + 2] * __shfl(v, 4 * j + 2, 64);
      u3 += row[4 * j + 3] * __shfl(v, 4 * j + 3, 64);
    }
    float u = (u0 + u1) + (u2 + u3);
    float ss = u * u;
#pragma unroll
    for (int m = 1; m < 64; m <<= 1) ss += __shfl_xor(ss, m, 64);
    v = u * rsqrtf(fmaxf(ss, 1e-30f));
  }
  float rowg[64];
#pragma unroll
  for (int j = 0; j < 16; j++)
    *(float4*)(rowg + 4 * j) = *(const float4*)(Gm + (size_t)i * SPAD + 4 * j);
  float u0 = 0.f, u1 = 0.f, u2 = 0.f, u3 = 0.f;
#pragma unroll
  for (int j = 0; j < 16; j++) {
    u0 += rowg[4 * j + 0] * __shfl(v, 4 * j + 0, 64);
    u1 += rowg[4 * j + 1] * __shfl(v, 4 * j + 1, 64);
    u2 += rowg[4 * j + 2] * __shfl(v, 4 * j + 2, 64);
    u3 += rowg[4 * j + 3] * __shfl(v, 4 * j + 3, 64);
  }
  float u = (u0 + u1) + (u2 + u3);
  float d = v * u;
#pragma unroll
  for (int m = 1; m < 64; m <<= 1) d += __shfl_xor(d, m, 64);
  return d;
}

// ---------------------------------------------------------------------------
// Fused spectral norms + lip: grid 130.
// ---------------------------------------------------------------------------
__global__ __launch_bounds__(256) void speclip_kernel(
    const float* __restrict__ w1, const float* __restrict__ w2,
    const float* __restrict__ gaw, float* __restrict__ invsig1,
    float* __restrict__ invsig2, float* __restrict__ lipv) {
  __shared__ float Sa[64 * SPAD];
  __shared__ float Sb[64 * SPAD];
  __shared__ float G[64 * SPAD];
  __shared__ float redm[4];
  int t = threadIdx.x;
  int blk = blockIdx.x;
  if (blk < 128) {
    int n = blk & 63;
    const float* A = (blk < 64) ? (w1 + (size_t)n * 4096) : (w2 + (size_t)n * 16384);
    int ncols = (blk < 64) ? 64 : 256;
    gram_mfma(A, ncols, Sa, G, t);        // G = A A^T (kept for Rayleigh)
    __syncthreads();
    mm_mfma(G, G, Sa, t, 1.f, 0, 0);      // G^2 -> Sa
    __syncthreads();
    mm_sq_norm(Sa, Sb, t, redm);  __syncthreads();  // G^4   -> Sb
    mm_sq_norm(Sb, Sa, t, redm);  __syncthreads();  // G^8   -> Sa
    mm_sq_norm(Sa, Sb, t, redm);  __syncthreads();  // G^16  -> Sb
    mm_sq_norm(Sb, Sa, t, redm);  __syncthreads();  // G^32  -> Sa
    mm_sq_norm(Sa, Sb, t, redm);  __syncthreads();  // G^64  -> Sb
    mm_sq_norm(Sb, Sa, t, redm);  __syncthreads();  // G^128 -> Sa
    if (t < 64) {
      float d = power_rayleigh(Sa, G, 2, t);
      if (t == 0) {
        float sg = sqrtf(fmaxf(d, 0.f));
        float inv = 1.0f / fmaxf(sg, 1e-6f);
        if (blk < 64) invsig1[n] = inv; else invsig2[n] = inv;
      }
    }
  } else {
    int l = blk - 128;
    const float* Wb = gaw + (size_t)l * 8192;
    for (int i = t; i < 1024; i += 256) {
      int r = i >> 4, qq = i & 15;
      *(float4*)(Sa + (size_t)r * SPAD + 4 * qq) = *(const float4*)(Wb + r * 64 + 4 * qq);
      *(float4*)(Sb + (size_t)r * SPAD + 4 * qq) = *(const float4*)(Wb + 4096 + r * 64 + 4 * qq);
    }
    __syncthreads();
    mm_mfma(Sa, Sb, G, t, 0.25f, 1, 1);   // Mt -> G (M = 0.25 Wq Wk^T + I, transposed)
    __syncthreads();
    mm_mfma(G, G, Sa, t, 1.f, 0, 0);      // M^T M -> Sa (kept for Rayleigh)
    __syncthreads();
    mm_sq_norm(Sa, Sb, t, redm);  __syncthreads();  // ^2  -> Sb
    mm_sq_norm(Sb, G, t, redm);   __syncthreads();  // ^4  -> G (Mt dead)
    mm_sq_norm(G, Sb, t, redm);   __syncthreads();  // ^8  -> Sb
    mm_sq_norm(Sb, G, t, redm);   __syncthreads();  // ^16 -> G
    mm_sq_norm(G, Sb, t, redm);   __syncthreads();  // ^32 -> Sb
    mm_sq_norm(Sb, G, t, redm);   __syncthreads();  // ^64 -> G
    if (t < 64) {
      float d = power_rayleigh(G, Sa, 2, t);
      if (t == 0) lipv[l] = sqrtf(fmaxf(d, 0.f)) + 5.0f;
    }
  }
}

// ---------------------------------------------------------------------------
// Fused h+conv: h = gelu(fused @ w1n + b1) stays in LDS; x = h @ w2n + b2.
// grid 512 = b*16+ng.
// ---------------------------------------------------------------------------
__global__ __launch_bounds__(256) void hconv_kernel(
    const float* __restrict__ fused, const float* __restrict__ w1,
    const float* __restrict__ b1, const float* __restrict__ invsig1,
    const float* __restrict__ w2, const float* __restrict__ b2,
    const float* __restrict__ invsig2, float* __restrict__ x) {
  __shared__ float fr[256];
  __shared__ float hr[4][64];
  int t = threadIdx.x;
  int blk = blockIdx.x;
  int b = blk >> 4, ng = blk & 15;
  int n0 = ng * 4;
  fr[t] = fused[(size_t)blk * 256 + t];
  __syncthreads();
  {
    int nl = t >> 6, j = t & 63;
    int n = n0 + nl;
    float is1 = invsig1[n];
    const float* fp = fr + nl * 64;
    const float* wp = w1 + (size_t)n * 4096 + j;
    float acc = 0.f;
    for (int i = 0; i < 64; i++) acc += fp[i] * wp[i * 64];
    acc = acc * is1 + b1[n * 64 + j];
    hr[nl][j] = 0.5f * acc * (1.0f + erff(acc * 0.70710678118654752440f));
  }
  __syncthreads();
  const float* w0p = w2 + ((size_t)(n0 + 0) * 64) * 256 + t;
  const float* w1p = w2 + ((size_t)(n0 + 1) * 64) * 256 + t;
  const float* w2p = w2 + ((size_t)(n0 + 2) * 64) * 256 + t;
  const float* w3p = w2 + ((size_t)(n0 + 3) * 64) * 256 + t;
  float a0 = 0.f, a1 = 0.f, a2 = 0.f, a3 = 0.f;
  for (int i = 0; i < 64; i++) {
    a0 += hr[0][i] * w0p[(size_t)i * 256];
    a1 += hr[1][i] * w1p[(size_t)i * 256];
    a2 += hr[2][i] * w2p[(size_t)i * 256];
    a3 += hr[3][i] * w3p[(size_t)i * 256];
  }
  float4 o;
  o.x = a0 * invsig2[n0 + 0] + b2[(n0 + 0) * 256 + t];
  o.y = a1 * invsig2[n0 + 1] + b2[(n0 + 1) * 256 + t];
  o.z = a2 * invsig2[n0 + 2] + b2[(n0 + 2) * 256 + t];
  o.w = a3 * invsig2[n0 + 3] + b2[(n0 + 3) * 256 + t];
  *(float4*)(x + ((size_t)b * 256 + t) * 64 + n0) = o;
}

// ---------------------------------------------------------------------------
// qk v5: MFMA + LDS-staged coalesced uint4 stores (kept from R5).
// ---------------------------------------------------------------------------
__global__ __launch_bounds__(256, 2) void qk_kernel(
    const float* __restrict__ x, const float* __restrict__ eqk,
    unsigned short* __restrict__ qhi, unsigned short* __restrict__ qlo,
    unsigned short* __restrict__ khi, unsigned short* __restrict__ klo) {
  __shared__ __align__(16) unsigned short TH[128 * 72];
  __shared__ __align__(16) unsigned short TL[128 * 72];
  int t = threadIdx.x;
  int blk = blockIdx.x;
  int xcd = blk & 7;
  int y = blk >> 3;
  int rh = y & 1;
  int c = (y >> 1) & 7;
  int b = (y >> 4) * 8 + xcd;
  int wv = t >> 6, l = t & 63;
  int m16 = l & 15, quad = l >> 4;
  int row0 = rh * 128 + wv * 32;

  bf8t ah[2][2], al[2][2];
#pragma unroll
  for (int rt = 0; rt < 2; rt++) {
    const float* xp = x + ((size_t)b * 256 + row0 + rt * 16 + m16) * 64 + quad * 8;
    split8(xp, &ah[rt][0], &al[rt][0]);
    split8(xp + 32, &ah[rt][1], &al[rt][1]);
  }
#pragma unroll
  for (int mat = 0; mat < 2; mat++) {
    const float* Wbase = eqk + ((size_t)(mat * 8 + c) * 64) * 64;
    unsigned short* ohi = mat ? khi : qhi;
    unsigned short* olo = mat ? klo : qlo;
#pragma unroll
    for (int ct = 0; ct < 4; ct++) {
      bf8t bh[2], bl[2];
      const float* wp = Wbase + (size_t)(ct * 16 + m16) * 64 + quad * 8;
      split8(wp, &bh[0], &bl[0]);
      split8(wp + 32, &bh[1], &bl[1]);
#pragma unroll
      for (int rt = 0; rt < 2; rt++) {
        f4t a = (f4t){0.f, 0.f, 0.f, 0.f};
        a = __builtin_amdgcn_mfma_f32_16x16x32_bf16(al[rt][0], bh[0], a, 0, 0, 0);
        a = __builtin_amdgcn_mfma_f32_16x16x32_bf16(ah[rt][0], bl[0], a, 0, 0, 0);
        a = __builtin_amdgcn_mfma_f32_16x16x32_bf16(ah[rt][0], bh[0], a, 0, 0, 0);
        a = __builtin_amdgcn_mfma_f32_16x16x32_bf16(al[rt][1], bh[1], a, 0, 0, 0);
        a = __builtin_amdgcn_mfma_f32_16x16x32_bf16(ah[rt][1], bl[1], a, 0, 0, 0);
        a = __builtin_amdgcn_mfma_f32_16x16x32_bf16(ah[rt][1], bh[1], a, 0, 0, 0);
#pragma unroll
        for (int j = 0; j < 4; j++) {
          int lr = (wv << 5) + rt * 16 + quad * 4 + j;   // 0..127 local row
          int f = ct * 16 + m16;
          float v = a[j];
          unsigned short hh = f2bf(v);
          TH[lr * 72 + f] = hh;
          TL[lr * 72 + f] = f2bf(v - bf2f(hh));
        }
      }
    }
    __syncthreads();
    // coalesced store: 128 rows x 64 ushorts contiguous in global
    size_t gbase = ((size_t)b * 8 + c) * 16384 + (size_t)rh * 8192;
#pragma unroll
    for (int k = 0; k < 4; k++) {
      int i = t + k * 256;           // uint4 index 0..1023
      int r = i >> 3, f8 = i & 7;
      *(uint4*)(ohi + gbase + (size_t)i * 8) = *(const uint4*)(TH + r * 72 + f8 * 8);
      *(uint4*)(olo + gbase + (size_t)i * 8) = *(const uint4*)(TL + r * 72 + f8 * 8);
    }
    if (mat == 0) __syncthreads();
  }
}

// ---------------------------------------------------------------------------
// Fused attn v9 (R2-proven, 60 VGPR): K hi/lo for both c's staged in LDS
// (64 KB, MFMA-fragment order), 2 phases of 8 tiles.
// ---------------------------------------------------------------------------
__global__ __launch_bounds__(512, 4) void attn_kernel(
    const unsigned short* __restrict__ qhi, const unsigned short* __restrict__ qlo,
    const unsigned short* __restrict__ khi, const unsigned short* __restrict__ klo,
    float* __restrict__ seP, float* __restrict__ mxb, float* __restrict__ rzb) {
  __shared__ uint4 KS4[4096];                    // 64 KB
  unsigned short* KS = (unsigned short*)KS4;
  float* sE = (float*)KS4;                       // alias (32*260 floats, 33 KB)
  int t = threadIdx.x;
  int blk = blockIdx.x;
  int xcd = blk & 7;
  int y = blk >> 3;
  int b = xcd * 4 + (y & 3);
  int cg = (y >> 2) & 3;
  int ng = y >> 4;
  int wave = t >> 6;       // 0..7
  int ci = wave >> 2;      // 0,1: which c of the cg pair
  int wv = wave & 3;       // 16-row sub-tile
  int l = t & 63;
  int m16 = l & 15, quad = l >> 4;
  int n0w = ng * 64 + wv * 16;
  int c = cg * 2 + ci;

  size_t slA = ((size_t)b * 8 + cg * 2) * 16384;   // cc=0 slice (ushort units)
  size_t slB = slA + 16384;                        // cc=1 slice
  size_t sl = ((size_t)b * 8 + c) * 16384;

  // Q fragments (global, once)
  const bf8t* qh = (const bf8t*)(qhi + sl + (size_t)(n0w + m16) * 64 + quad * 8);
  const bf8t* ql = (const bf8t*)(qlo + sl + (size_t)(n0w + m16) * 64 + quad * 8);
  bf8t ah0 = qh[0], ah1 = qh[4];
  bf8t al0 = ql[0], al1 = ql[4];

  // staging decode (entry e = it*512 + t; bits [3:0]=m16 [5:4]=quad [6]=half
  // [8:7]=tl_lo [9]=tl_hi(it&1) [10]=hilo [11]=cc). LDS ushort off = e*8.
  int sthalf = (t >> 6) & 1;
  int tllo = (t >> 7) & 3;
  int srcbase = tllo * 1024 + m16 * 64 + sthalf * 32 + quad * 8;  // ushort
  int dstbase = t * 8;                                            // ushort

  // compute-side LDS offsets (ushorts): tile stride 1024, half +512, hilo +8192, c +16384
  int lane8 = (quad * 16 + m16) * 8;
  int cbase = ci * 16384;

  f4t acc[16];
#pragma unroll
  for (int mt = 0; mt < 16; mt++) acc[mt] = (f4t){0.f, 0.f, 0.f, 0.f};

#pragma unroll
  for (int p = 0; p < 2; p++) {
    if (p) __syncthreads();               // all waves done reading previous phase
    int pb = srcbase + p * 8192;          // phase row offset (8 tiles * 16 rows * 64)
#pragma unroll
    for (int g = 0; g < 2; g++) {         // g = cc
      const unsigned short* bhp = khi + (g ? slB : slA) + pb;
      const unsigned short* blp = klo + (g ? slB : slA) + pb;
      uint4 v0 = *(const uint4*)(bhp);            // it=g*4+0: hilo0 tlhi0
      uint4 v1 = *(const uint4*)(bhp + 4096);     // it=g*4+1: hilo0 tlhi1
      uint4 v2 = *(const uint4*)(blp);            // it=g*4+2: hilo1 tlhi0
      uint4 v3 = *(const uint4*)(blp + 4096);     // it=g*4+3: hilo1 tlhi1
      *(uint4*)(KS + dstbase + (g * 4 + 0) * 4096) = v0;
      *(uint4*)(KS + dstbase + (g * 4 + 1) * 4096) = v1;
      *(uint4*)(KS + dstbase + (g * 4 + 2) * 4096) = v2;
      *(uint4*)(KS + dstbase + (g * 4 + 3) * 4096) = v3;
    }
    __syncthreads();                      // staging visible
#pragma unroll
    for (int tl = 0; tl < 8; tl++) {
      int mt = p * 8 + tl;
      int tb = cbase + tl * 1024 + lane8;
      bf8t bh0 = *(const bf8t*)(KS + tb);
      bf8t bh1 = *(const bf8t*)(KS + tb + 512);
      bf8t bl0 = *(const bf8t*)(KS + tb + 8192);
      bf8t bl1 = *(const bf8t*)(KS + tb + 8704);
      f4t a = acc[mt];
      a = __builtin_amdgcn_mfma_f32_16x16x32_bf16(al0, bh0, a, 0, 0, 0);
      a = __builtin_amdgcn_mfma_f32_16x16x32_bf16(ah0, bl0, a, 0, 0, 0);
      a = __builtin_amdgcn_mfma_f32_16x16x32_bf16(ah0, bh0, a, 0, 0, 0);
      a = __builtin_amdgcn_mfma_f32_16x16x32_bf16(al1, bh1, a, 0, 0, 0);
      a = __builtin_amdgcn_mfma_f32_16x16x32_bf16(ah1, bl1, a, 0, 0, 0);
      a = __builtin_amdgcn_mfma_f32_16x16x32_bf16(ah1, bh1, a, 0, 0, 0);
      acc[mt] = a;
    }
  }
  // softmax per output row j; converts acc in place to probs (e * 1/z)
#pragma unroll
  for (int j = 0; j < 4; j++) {
    float mx = -FLT_MAX;
#pragma unroll
    for (int mt = 0; mt < 16; mt++) mx = fmaxf(mx, acc[mt][j]);
    mx = fmaxf(mx, __shfl_xor(mx, 1, 64));
    mx = fmaxf(mx, __shfl_xor(mx, 2, 64));
    mx = fmaxf(mx, __shfl_xor(mx, 4, 64));
    mx = fmaxf(mx, __shfl_xor(mx, 8, 64));
    float mxl = mx * 0.125f;
    float z = 0.f;
#pragma unroll
    for (int mt = 0; mt < 16; mt++) {
      float e = expf(acc[mt][j] * 0.125f - mxl);
      acc[mt][j] = e;
      z += e;
    }
    z += __shfl_xor(z, 1, 64);
    z += __shfl_xor(z, 2, 64);
    z += __shfl_xor(z, 4, 64);
    z += __shfl_xor(z, 8, 64);
    int n = n0w + quad * 4 + j;
    if (m16 == 0) {
      mxb[((size_t)b * 8 + c) * 256 + n] = mxl;
      rzb[((size_t)b * 8 + c) * 256 + n] = z;
    }
    float zi = 1.0f / z;
#pragma unroll
    for (int mt = 0; mt < 16; mt++) acc[mt][j] *= zi;
  }
  __syncthreads();   // KS reads done everywhere; sE alias now safe
  // cross-c combine + coalesced seP store, two 32-row passes through LDS
  for (int half = 0; half < 2; half++) {
    if (ci == 0 && (wv >> 1) == half) {
      int r0 = (wv & 1) * 16;
#pragma unroll
      for (int mt = 0; mt < 16; mt++)
#pragma unroll
        for (int j = 0; j < 4; j++)
          sE[(r0 + quad * 4 + j) * 260 + mt * 16 + m16] = acc[mt][j];
    }
    __syncthreads();
    if (ci == 1 && (wv >> 1) == half) {
      int r0 = (wv & 1) * 16;
#pragma unroll
      for (int mt = 0; mt < 16; mt++)
#pragma unroll
        for (int j = 0; j < 4; j++)
          sE[(r0 + quad * 4 + j) * 260 + mt * 16 + m16] += acc[mt][j];
    }
    __syncthreads();
    float4* dst4 = (float4*)(seP + (((size_t)cg * 32 + b) * 256 + ng * 64 + half * 32) * 256);
    for (int i = t; i < 2048; i += 512) {
      int r = i >> 6, c4 = i & 63;
      dst4[i] = *(const float4*)(sE + r * 260 + c4 * 4);
    }
    if (half == 0) __syncthreads();
  }
}

// ---------------------------------------------------------------------------
// topsel v2: grid 256 = b*8+rg (32 rows/block; was 128 blocks = half the CUs
// idle). Merge candidate arrays padded to stride 49 (odd): v1's cv[64][24]
// had row stride 24 -> (24r)%32 in {0,8,16,24} = 16-way bank conflict in the
// merge loop (SQ_LDS_BANK_CONFLICT 544K). Scan: 8 lanes/row x 32 cols.
// LDS 77 KB -> ~45 KB. Selection semantics identical (strict-greater insert,
// lowest-index tie-break). colsum zeroing folded (disjoint 256-fl slices).
// ---------------------------------------------------------------------------
__global__ __launch_bounds__(256) void topsel_kernel(
    const float* __restrict__ seP, int* __restrict__ idx7,
    float* __restrict__ colsum) {
  __shared__ float seL[32 * 260];
  __shared__ float cv[32][49];
  __shared__ int cidx[32][49];
  int t = threadIdx.x;
  int b = blockIdx.x >> 3, rg = blockIdx.x & 7;
  int n0 = rg * 32;
  colsum[(size_t)b * 2048 + rg * 256 + t] = 0.f;
  const float* s0 = seP + ((size_t)b * 256 + n0) * 256;
  const float* s1 = seP + ((size_t)(32 + b) * 256 + n0) * 256;
  const float* s2 = seP + ((size_t)(64 + b) * 256 + n0) * 256;
  const float* s3 = seP + ((size_t)(96 + b) * 256 + n0) * 256;
  for (int i = t; i < 2048; i += 256) {
    int m4 = i & 63, r = i >> 6;
    float4 v0 = ((const float4*)(s0 + (size_t)r * 256))[m4];
    float4 v1 = ((const float4*)(s1 + (size_t)r * 256))[m4];
    float4 v2 = ((const float4*)(s2 + (size_t)r * 256))[m4];
    float4 v3 = ((const float4*)(s3 + (size_t)r * 256))[m4];
    float4 s;
    s.x = (v0.x + v1.x) + (v2.x + v3.x);
    s.y = (v0.y + v1.y) + (v2.y + v3.y);
    s.z = (v0.z + v1.z) + (v2.z + v3.z);
    s.w = (v0.w + v1.w) + (v2.w + v3.w);
    *(float4*)(seL + r * 260 + m4 * 4) = s;
  }
  __syncthreads();
  {
    int r = t >> 3, q8 = t & 7;
    float tv[6]; int ti[6];
#pragma unroll
    for (int s = 0; s < 6; s++) { tv[s] = -FLT_MAX; ti[s] = 1 << 30; }
    for (int i = 0; i < 32; i++) {
      int m = 8 * i + q8;
      float val = seL[r * 260 + m];
      if (val > tv[5]) {
        tv[5] = val; ti[5] = m;
#pragma unroll
        for (int s = 5; s > 0; s--) {
          if (tv[s] > tv[s - 1]) {
            float tmv = tv[s]; tv[s] = tv[s - 1]; tv[s - 1] = tmv;
            int tmi = ti[s]; ti[s] = ti[s - 1]; ti[s - 1] = tmi;
          }
        }
      }
    }
#pragma unroll
    for (int s = 0; s < 6; s++) { cv[r][q8 * 6 + s] = tv[s]; cidx[r][q8 * 6 + s] = ti[s]; }
  }
  __syncthreads();
  if (t < 32) {
    int r = t, n = n0 + r;
    int sel[7];
    for (int round = 0; round < 6; round++) {
      float best = -FLT_MAX; int bi = 1 << 30, bs = 0;
      for (int j = 0; j < 48; j++) {
        float v = cv[r][j]; int id = cidx[r][j];
        if (v > best || (v == best && id < bi)) { best = v; bi = id; bs = j; }
      }
      sel[round] = bi;
      cv[r][bs] = -FLT_MAX;
    }
    bool dup = false;
#pragma unroll
    for (int j = 0; j < 6; j++) dup = dup || (sel[j] == n);
    sel[6] = dup ? -1 : n;
#pragma unroll
    for (int j = 0; j < 7; j++) idx7[((size_t)b * 256 + n) * 7 + j] = sel[j];
  }
}

// ---------------------------------------------------------------------------
// nr values: recompute <=7 attn entries from the stored bf16 3-term split
// (consistent with attn's mxb/rzb), row-normalize, atomic colsum.
// ---------------------------------------------------------------------------
__global__ __launch_bounds__(256) void nr_kernel(
    const unsigned short* __restrict__ qhi, const unsigned short* __restrict__ qlo,
    const unsigned short* __restrict__ khi, const unsigned short* __restrict__ klo,
    const float* __restrict__ mxb, const float* __restrict__ rzb,
    const int* __restrict__ idx7, float* __restrict__ nrv,
    float* __restrict__ colsum) {
  __shared__ int idxs[7];
  __shared__ float attL[56];
  int t = threadIdx.x;
  int b = blockIdx.x >> 8, n = blockIdx.x & 255;
  if (t < 7) idxs[t] = idx7[(size_t)blockIdx.x * 7 + t];
  __syncthreads();
  int task = t >> 2, l4 = t & 3;
  if (task < 56) {
    int c = task / 7, j = task - c * 7;
    int d = idxs[j];
    float s = 0.f;
    if (d >= 0) {
      size_t qo = (((size_t)b * 8 + c) * 256 + n) * 64 + l4 * 16;
      size_t ko = (((size_t)b * 8 + c) * 256 + d) * 64 + l4 * 16;
      const uint4* qh4 = (const uint4*)(qhi + qo);
      const uint4* ql4 = (const uint4*)(qlo + qo);
      const uint4* kh4 = (const uint4*)(khi + ko);
      const uint4* kl4 = (const uint4*)(klo + ko);
#pragma unroll
      for (int g = 0; g < 2; g++) {
        uint4 uqh = qh4[g], uql = ql4[g], ukh = kh4[g], ukl = kl4[g];
        s += dot3_pair(uqh.x, uql.x, ukh.x, ukl.x);
        s += dot3_pair(uqh.y, uql.y, ukh.y, ukl.y);
        s += dot3_pair(uqh.z, uql.z, ukh.z, ukl.z);
        s += dot3_pair(uqh.w, uql.w, ukh.w, ukl.w);
      }
    }
    s += __shfl_xor(s, 1, 64);
    s += __shfl_xor(s, 2, 64);
    if (l4 == 0) {
      float att = 0.f;
      if (d >= 0) {
        float logit = s * 0.125f;
        att = expf(logit - mxb[((size_t)b * 8 + c) * 256 + n]) / rzb[((size_t)b * 8 + c) * 256 + n];
      }
      attL[task] = att;
    }
  }
  __syncthreads();
  if (t < 8) {
    float rs = 0.f;
#pragma unroll
    for (int j = 0; j < 7; j++) rs += attL[t * 7 + j];
    float ri = 1.0f / (rs + 1e-6f);
#pragma unroll
    for (int j = 0; j < 7; j++) {
      float nv = attL[t * 7 + j] * ri;
      nrv[(((size_t)b * 8 + t) * 256 + n) * 7 + j] = nv;
      int d = idxs[j];
      if (d >= 0) atomicAdd(&colsum[((size_t)b * 8 + t) * 256 + d], nv);
    }
  }
}

// ---------------------------------------------------------------------------
// edge v2 (R6-proven): grid 2048, branchless gather, 28 KB LDS.
// ---------------------------------------------------------------------------
__global__ __launch_bounds__(256, 5) void edge_kernel(
    const int* __restrict__ idx7, const float* __restrict__ nrv,
    const float* __restrict__ colsum, unsigned short* __restrict__ edge) {
  __shared__ unsigned short ncT[256 * 32];   // 16 KB
  __shared__ short idxL[256 * 8];            // 4 KB
  __shared__ float nrvL[256 * 8];            // 8 KB
  int t = threadIdx.x;
  int blk = blockIdx.x;
  int b = blk >> 6, c = (blk >> 3) & 7, mq = blk & 7;
  int m0 = mq * 32;
  for (int i = t; i < 4096; i += 256) ((unsigned int*)ncT)[i] = 0u;
  for (int i = t; i < 2048; i += 256) {
    int r = i >> 3, j = i & 7;
    if (j < 7) {
      idxL[i] = (short)idx7[(size_t)b * 1792 + r * 7 + j];
      nrvL[i] = nrv[((size_t)b * 8 + c) * 1792 + r * 7 + j];
    } else {
      idxL[i] = -1;
      nrvL[i] = 0.f;
    }
  }
  __syncthreads();
  for (int i = t; i < 224; i += 256) {
    int mi = i / 7, j = i - mi * 7;
    int m = m0 + mi;
    int d = idxL[m * 8 + j];
    if (d >= 0) {
      float cs = colsum[((size_t)b * 8 + c) * 256 + d];
      ncT[d * 32 + mi] = f2bf(nrvL[m * 8 + j] / (cs + 1e-6f));
    }
  }
  __syncthreads();
  int wv = t >> 6, l = t & 63;
  int qtr = l >> 4, p = l & 15;
  const unsigned int* ncP = (const unsigned int*)ncT;
  unsigned int* eb = (unsigned int*)(edge + (((size_t)b * 8 + c) * 256) * 256);
#pragma unroll 4
  for (int nn = 0; nn < 16; nn++) {
    int n = nn * 16 + wv * 4 + qtr;
    int4 iv = *(const int4*)(idxL + n * 8);
    float4 w0 = *(const float4*)(nrvL + n * 8);
    float4 w1 = *(const float4*)(nrvL + n * 8 + 4);
    // branchless: d=-1 -> row 255, weight is exactly 0
    unsigned p0 = ncP[(iv.x & 255) * 16 + p];
    unsigned p1 = ncP[((iv.x >> 16) & 255) * 16 + p];
    unsigned p2 = ncP[(iv.y & 255) * 16 + p];
    unsigned p3 = ncP[((iv.y >> 16) & 255) * 16 + p];
    unsigned p4 = ncP[(iv.z & 255) * 16 + p];
    unsigned p5 = ncP[((iv.z >> 16) & 255) * 16 + p];
    unsigned p6 = ncP[(iv.w & 255) * 16 + p];
    float a0 = w0.x * bf2f_lo(p0) + w0.y * bf2f_lo(p1) + w0.z * bf2f_lo(p2)
             + w0.w * bf2f_lo(p3) + w1.x * bf2f_lo(p4) + w1.y * bf2f_lo(p5)
             + w1.z * bf2f_lo(p6);
    float a1 = w0.x * bf2f_hi(p0) + w0.y * bf2f_hi(p1) + w0.z * bf2f_hi(p2)
             + w0.w * bf2f_hi(p3) + w1.x * bf2f_hi(p4) + w1.y * bf2f_hi(p5)
             + w1.z * bf2f_hi(p6);
    unsigned int packo = (unsigned int)f2bf(a0) | ((unsigned int)f2bf(a1) << 16);
    eb[n * 128 + (m0 >> 1) + p] = packo;
  }
}

// ---------------------------------------------------------------------------
// qkx v3: fused xs + qg + kg (row-major). grid 128.
// ---------------------------------------------------------------------------
static __device__ __forceinline__ float selu1(float v) {
  float e = (v > 0.f) ? v : expm1f(v);
  return 1.0f / (1.0f + expf(-e));
}
__global__ __launch_bounds__(256, 1) void qkx_kernel(
    const float* __restrict__ x, const float* __restrict__ gaw,
    const float* __restrict__ gab, int l, float* __restrict__ xs,
    float* __restrict__ qg, float* __restrict__ kg) {
  __shared__ float xsL[64 * 64];
  int t = threadIdx.x;
  int b = blockIdx.x >> 2, nt = blockIdx.x & 3;
  int f = t & 63, part = t >> 6;
  float wq[64], wk[64];
  const float4* Wq4 = (const float4*)(gaw + (size_t)l * 8192 + f * 64);
  const float4* Wk4 = (const float4*)(gaw + (size_t)l * 8192 + (64 + f) * 64);
#pragma unroll
  for (int j = 0; j < 16; j++) {
    float4 aa = Wq4[j];
    wq[4 * j + 0] = aa.x; wq[4 * j + 1] = aa.y; wq[4 * j + 2] = aa.z; wq[4 * j + 3] = aa.w;
    float4 bb = Wk4[j];
    wk[4 * j + 0] = bb.x; wk[4 * j + 1] = bb.y; wk[4 * j + 2] = bb.z; wk[4 * j + 3] = bb.w;
  }
  float bq = gab[l * 128 + f], bk = gab[l * 128 + 64 + f];
  for (int i = t; i < 1024; i += 256) {
    float4 v = ((const float4*)(x + ((size_t)b * 256 + nt * 64) * 64))[i];
    float4 o;
    o.x = selu1(v.x); o.y = selu1(v.y); o.z = selu1(v.z); o.w = selu1(v.w);
    ((float4*)xsL)[i] = o;
    ((float4*)(xs + ((size_t)b * 256 + nt * 64) * 64))[i] = o;
  }
  __syncthreads();
  for (int i = 0; i < 16; i++) {
    int nl = part * 16 + i;
    const float4* xr = (const float4*)(xsL + nl * 64);
    float aq = 0.f, ak = 0.f;
#pragma unroll
    for (int j = 0; j < 16; j++) {
      float4 v = xr[j];
      aq += v.x * wq[4 * j] + v.y * wq[4 * j + 1] + v.z * wq[4 * j + 2] + v.w * wq[4 * j + 3];
      ak += v.x * wk[4 * j] + v.y * wk[4 * j + 1] + v.z * wk[4 * j + 2] + v.w * wk[4 * j + 3];
    }
    int n = nt * 64 + nl;
    qg[((size_t)b * 256 + n) * 64 + f] = aq + bq;
    kg[((size_t)b * 256 + n) * 64 + f] = ak + bk;
  }
}

// ---------------------------------------------------------------------------
// upd v2: ga_attn fused in (kept from R4 — fewer launches).
// ---------------------------------------------------------------------------
__global__ __launch_bounds__(256) void upd_kernel(
    const float* __restrict__ qg, const float* __restrict__ kg,
    const unsigned short* __restrict__ edge,
    const float* __restrict__ xs, const float* __restrict__ gaww,
    const float* __restrict__ lipv, int l, float* __restrict__ x) {
  __shared__ float tt[4][8][260];
  __shared__ float ne3[4][256];
  __shared__ float parts[4][4][64];
  __shared__ float dred[32][8];
  __shared__ float dinv[4][8];
  __shared__ float wcL[8];
  __shared__ float lipi;
  __shared__ float qgL[4][64];
  __shared__ float rred[2][4][4];   // [max/sum][row][wave]
  int t = threadIdx.x;
  int b = blockIdx.x >> 6, nq = blockIdx.x & 63;
  int n0 = nq * 4;
  int wave = t >> 6;
  if (t == 0) {
    float s = 0.f;
    float wtmp[8];
    for (int c = 0; c < 8; c++) { wtmp[c] = gaww[l * 8 + c]; s += wtmp[c]; }
    for (int c = 0; c < 8; c++) wcL[c] = wtmp[c] / s;
    lipi = 1.0f / lipv[l];
  }
  {
    int r = t >> 6, f = t & 63;
    qgL[r][f] = qg[((size_t)b * 256 + n0 + r) * 64 + f];
  }
  __syncthreads();
  // ---- inline ga_attn: thread t = column m; 4 rows ----
  float d0 = 0.f, d1 = 0.f, d2 = 0.f, d3 = 0.f;
  {
    const float4* kr = (const float4*)(kg + ((size_t)b * 256 + t) * 64);
#pragma unroll
    for (int j = 0; j < 16; j++) {
      float4 kv = kr[j];
      float4 q0 = ((const float4*)qgL[0])[j];
      float4 q1 = ((const float4*)qgL[1])[j];
      float4 q2 = ((const float4*)qgL[2])[j];
      float4 q3 = ((const float4*)qgL[3])[j];
      d0 += q0.x * kv.x + q0.y * kv.y + q0.z * kv.z + q0.w * kv.w;
      d1 += q1.x * kv.x + q1.y * kv.y + q1.z * kv.z + q1.w * kv.w;
      d2 += q2.x * kv.x + q2.y * kv.y + q2.z * kv.z + q2.w * kv.w;
      d3 += q3.x * kv.x + q3.y * kv.y + q3.z * kv.z + q3.w * kv.w;
    }
  }
  d0 *= 0.125f; d1 *= 0.125f; d2 *= 0.125f; d3 *= 0.125f;
  {
    float m0 = d0, m1 = d1, m2 = d2, m3 = d3;
#pragma unroll
    for (int mm = 1; mm < 64; mm <<= 1) {
      m0 = fmaxf(m0, __shfl_xor(m0, mm, 64));
      m1 = fmaxf(m1, __shfl_xor(m1, mm, 64));
      m2 = fmaxf(m2, __shfl_xor(m2, mm, 64));
      m3 = fmaxf(m3, __shfl_xor(m3, mm, 64));
    }
    if ((t & 63) == 0) {
      rred[0][0][wave] = m0; rred[0][1][wave] = m1;
      rred[0][2][wave] = m2; rred[0][3][wave] = m3;
    }
  }
  __syncthreads();
  {
    float g0 = fmaxf(fmaxf(rred[0][0][0], rred[0][0][1]), fmaxf(rred[0][0][2], rred[0][0][3]));
    float g1 = fmaxf(fmaxf(rred[0][1][0], rred[0][1][1]), fmaxf(rred[0][1][2], rred[0][1][3]));
    float g2 = fmaxf(fmaxf(rred[0][2][0], rred[0][2][1]), fmaxf(rred[0][2][2], rred[0][2][3]));
    float g3 = fmaxf(fmaxf(rred[0][3][0], rred[0][3][1]), fmaxf(rred[0][3][2], rred[0][3][3]));
    d0 = expf(d0 - g0); d1 = expf(d1 - g1); d2 = expf(d2 - g2); d3 = expf(d3 - g3);
    float s0 = d0, s1 = d1, s2 = d2, s3 = d3;
#pragma unroll
    for (int mm = 1; mm < 64; mm <<= 1) {
      s0 += __shfl_xor(s0, mm, 64);
      s1 += __shfl_xor(s1, mm, 64);
      s2 += __shfl_xor(s2, mm, 64);
      s3 += __shfl_xor(s3, mm, 64);
    }
    if ((t & 63) == 0) {
      rred[1][0][wave] = s0; rred[1][1][wave] = s1;
      rred[1][2][wave] = s2; rred[1][3][wave] = s3;
    }
  }
  __syncthreads();
  float av[4];
  {
    float z0 = (rred[1][0][0] + rred[1][0][1]) + (rred[1][0][2] + rred[1][0][3]);
    float z1 = (rred[1][1][0] + rred[1][1][1]) + (rred[1][1][2] + rred[1][1][3]);
    float z2 = (rred[1][2][0] + rred[1][2][1]) + (rred[1][2][2] + rred[1][2][3]);
    float z3 = (rred[1][3][0] + rred[1][3][1]) + (rred[1][3][2] + rred[1][3][3]);
    av[0] = d0 / z0; av[1] = d1 / z1; av[2] = d2 / z2; av[3] = d3 / z3;
  }
  // ---- ne pipeline ----
#pragma unroll
  for (int r = 0; r < 4; r++) {
#pragma unroll
    for (int c = 0; c < 8; c++)
      tt[r][c][t] = av[r] * bf2f(edge[(((size_t)b * 8 + c) * 256 + n0 + r) * 256 + t]);
  }
  __syncthreads();
  {
    int rc = t >> 3, i = t & 7;
    int r = rc >> 3, c = rc & 7;
    float p = 0.f;
#pragma unroll
    for (int kq = 0; kq < 32; kq++) p += tt[r][c][i + 8 * kq];
    dred[rc][i] = p;
  }
  __syncthreads();
  if (t < 32) {
    float s = 0.f;
#pragma unroll
    for (int i = 0; i < 8; i++) s += dred[t][i];
    dinv[t >> 3][t & 7] = 1.0f / (s + 1e-6f);
  }
  __syncthreads();
#pragma unroll
  for (int r = 0; r < 4; r++) {
    float s = 0.f;
#pragma unroll
    for (int c = 0; c < 8; c++) s += wcL[c] * tt[r][c][t] * dinv[r][c];
    ne3[r][t] = s;
  }
  __syncthreads();
  {
    int f = t & 63, part = t >> 6;
    float a0 = 0.f, a1 = 0.f, a2 = 0.f, a3 = 0.f;
    for (int mm = 0; mm < 64; mm++) {
      int m = part * 64 + mm;
      float xv = xs[((size_t)b * 256 + m) * 64 + f];
      a0 += ne3[0][m] * xv;
      a1 += ne3[1][m] * xv;
      a2 += ne3[2][m] * xv;
      a3 += ne3[3][m] * xv;
    }
    parts[0][part][f] = a0;
    parts[1][part][f] = a1;
    parts[2][part][f] = a2;
    parts[3][part][f] = a3;
  }
  __syncthreads();
  {
    int r = t >> 6, f = t & 63;
    float dx = parts[r][0][f] + parts[r][1][f] + parts[r][2][f] + parts[r][3][f];
    x[((size_t)b * 256 + n0 + r) * 64 + f] += dx * lipi;
  }
}

// ---------------------------------------------------------------------------
extern "C" void kernel_launch(void* const* d_in, const int* in_sizes, int n_in,
                              void* d_out, int out_size, void* d_ws, size_t ws_size,
                              hipStream_t stream) {
  (void)in_sizes; (void)n_in; (void)out_size; (void)ws_size;
  const float* fused = (const float*)d_in[0];
  const float* w1 = (const float*)d_in[1];
  const float* b1 = (const float*)d_in[2];
  const float* w2 = (const float*)d_in[3];
  const float* b2 = (const float*)d_in[4];
  const float* eqk = (const float*)d_in[5];
  const float* gaw = (const float*)d_in[6];
  const float* gab = (const float*)d_in[7];
  const float* gaww = (const float*)d_in[8];
  float* x = (float*)d_out;  // x lives in d_out (B,ND,NF)=(32,256,64); fully overwritten.
  char* ws = (char*)d_ws;
  size_t off = 0;
  auto alloc = [&](size_t bytes) -> char* {
    char* p = ws + off;
    off += (bytes + 1023) & ~(size_t)1023;
    return p;
  };
  float* invsig1 = (float*)alloc(64 * 4);
  float* invsig2 = (float*)alloc(64 * 4);
  float* lipv = (float*)alloc(2 * 4);
  unsigned short* qhi = (unsigned short*)alloc((size_t)32 * 8 * 256 * 64 * 2);
  unsigned short* qlo = (unsigned short*)alloc((size_t)32 * 8 * 256 * 64 * 2);
  unsigned short* khi = (unsigned short*)alloc((size_t)32 * 8 * 256 * 64 * 2);
  unsigned short* klo = (unsigned short*)alloc((size_t)32 * 8 * 256 * 64 * 2);
  // seP (4 partials, 33.5 MB) aliases edge (33.5 MB): seP dead after topsel.
  char* sep_edge = alloc((size_t)4 * 32 * 256 * 256 * 4);
  float* seP = (float*)sep_edge;
  unsigned short* edge = (unsigned short*)sep_edge;
  float* mxb = (float*)alloc((size_t)65536 * 4);
  float* rzb = (float*)alloc((size_t)65536 * 4);
  int* idx7 = (int*)alloc((size_t)8192 * 7 * 4);
  float* nrv = (float*)alloc((size_t)65536 * 7 * 4);
  float* colsum = (float*)alloc((size_t)65536 * 4);
  float* xs = (float*)alloc((size_t)524288 * 4);
  float* qg = (float*)alloc((size_t)524288 * 4);
  float* kg = (float*)alloc((size_t)524288 * 4);

  speclip_kernel<<<130, 256, 0, stream>>>(w1, w2, gaw, invsig1, invsig2, lipv);
  hconv_kernel<<<512, 256, 0, stream>>>(fused, w1, b1, invsig1, w2, b2, invsig2, x);
  qk_kernel<<<512, 256, 0, stream>>>(x, eqk, qhi, qlo, khi, klo);
  attn_kernel<<<512, 512, 0, stream>>>(qhi, qlo, khi, klo, seP, mxb, rzb);
  topsel_kernel<<<256, 256, 0, stream>>>(seP, idx7, colsum);
  nr_kernel<<<8192, 256, 0, stream>>>(qhi, qlo, khi, klo, mxb, rzb, idx7, nrv, colsum);
  edge_kernel<<<2048, 256, 0, stream>>>(idx7, nrv, colsum, edge);
  for (int l = 0; l < 2; l++) {
    qkx_kernel<<<128, 256, 0, stream>>>(x, gaw, gab, l, xs, qg, kg);
    upd_kernel<<<2048, 256, 0, stream>>>(qg, kg, edge, xs, gaww, lipv, l, x);
  }
}

// Round 10
// 338.916 us; speedup vs baseline: 1.0388x; 1.0388x over previous
//
#include <hip/hip_runtime.h>
#include <float.h>
#include <math.h>

// Problem constants: B=32, NF=64, FD=64, ND=256, C=8, K=6, L=2, scale=1/8.

typedef short bf8t __attribute__((ext_vector_type(8)));   // 8 bf16 in 4 VGPRs
typedef float f4t __attribute__((ext_vector_type(4)));

static __device__ __forceinline__ unsigned short f2bf(float x) {
  union { float f; unsigned u; } v; v.f = x;
  unsigned r = (v.u + 0x7FFFu + ((v.u >> 16) & 1u)) >> 16;
  return (unsigned short)r;
}
static __device__ __forceinline__ float bf2f(unsigned short s) {
  union { unsigned u; float f; } v; v.u = ((unsigned)s) << 16; return v.f;
}
static __device__ __forceinline__ float bf2f_lo(unsigned u) {
  union { unsigned u; float f; } v; v.u = u << 16; return v.f;
}
static __device__ __forceinline__ float bf2f_hi(unsigned u) {
  union { unsigned u; float f; } v; v.u = u & 0xFFFF0000u; return v.f;
}
// 2 packed elems of the 3-term split dot: qh*(kh+kl) + ql*kh
static __device__ __forceinline__ float dot3_pair(unsigned uqh, unsigned uql,
                                                  unsigned ukh, unsigned ukl) {
  float s = bf2f_lo(uqh) * (bf2f_lo(ukh) + bf2f_lo(ukl)) + bf2f_lo(uql) * bf2f_lo(ukh);
  s += bf2f_hi(uqh) * (bf2f_hi(ukh) + bf2f_hi(ukl)) + bf2f_hi(uql) * bf2f_hi(ukh);
  return s;
}
// split 8 fp32 into hi/lo bf16 fragments
static __device__ __forceinline__ void split8(const float* __restrict__ p,
                                              bf8t* hi, bf8t* lo) {
  float4 v0 = *(const float4*)(p);
  float4 v1 = *(const float4*)(p + 4);
  float v[8] = {v0.x, v0.y, v0.z, v0.w, v1.x, v1.y, v1.z, v1.w};
#pragma unroll
  for (int j = 0; j < 8; j++) {
    unsigned short h = f2bf(v[j]);
    (*hi)[j] = (short)h;
    (*lo)[j] = (short)f2bf(v[j] - bf2f(h));
  }
}
// split one f32 into hi/lo bf16 stored at idx
static __device__ __forceinline__ void store_split(
    unsigned short* __restrict__ h, unsigned short* __restrict__ lo,
    int idx, float v) {
  unsigned short hh = f2bf(v);
  h[idx] = hh;
  lo[idx] = f2bf(v - bf2f(hh));
}

#define SPH 72    // LDS ushort row stride for speclip bf16-resident matrices

// ---------------------------------------------------------------------------
// speclip v2 helpers: matrices live in LDS as bf16 hi/lo (split ONCE at write;
// v1 re-split 80 f32/thread/mm from f32 LDS = ~800 VALU ops vs 24 MFMA —
// VALU-bound, m80 pattern). Fragments are direct ds_read_b128.
// ---------------------------------------------------------------------------
static __device__ __forceinline__ void mm_mfma_bf(
    const unsigned short* __restrict__ Ah, const unsigned short* __restrict__ Al,
    const unsigned short* __restrict__ Bh, const unsigned short* __restrict__ Bl,
    unsigned short* __restrict__ Ch, unsigned short* __restrict__ Cl,
    int t, float scale, int addI, int transposeStore) {
  int wv = t >> 6, l = t & 63;
  int m16 = l & 15, quad = l >> 4;
  int abase = (16 * wv + m16) * SPH + quad * 8;
  bf8t ah0 = *(const bf8t*)(Ah + abase);
  bf8t ah1 = *(const bf8t*)(Ah + abase + 32);
  bf8t al0 = *(const bf8t*)(Al + abase);
  bf8t al1 = *(const bf8t*)(Al + abase + 32);
  f4t acc[4];
#pragma unroll
  for (int ct = 0; ct < 4; ct++) {
    int bbase = (ct * 16 + m16) * SPH + quad * 8;
    bf8t bh0 = *(const bf8t*)(Bh + bbase);
    bf8t bh1 = *(const bf8t*)(Bh + bbase + 32);
    bf8t bl0 = *(const bf8t*)(Bl + bbase);
    bf8t bl1 = *(const bf8t*)(Bl + bbase + 32);
    f4t a = (f4t){0.f, 0.f, 0.f, 0.f};
    a = __builtin_amdgcn_mfma_f32_16x16x32_bf16(al0, bh0, a, 0, 0, 0);
    a = __builtin_amdgcn_mfma_f32_16x16x32_bf16(ah0, bl0, a, 0, 0, 0);
    a = __builtin_amdgcn_mfma_f32_16x16x32_bf16(ah0, bh0, a, 0, 0, 0);
    a = __builtin_amdgcn_mfma_f32_16x16x32_bf16(al1, bh1, a, 0, 0, 0);
    a = __builtin_amdgcn_mfma_f32_16x16x32_bf16(ah1, bl1, a, 0, 0, 0);
    a = __builtin_amdgcn_mfma_f32_16x16x32_bf16(ah1, bh1, a, 0, 0, 0);
    acc[ct] = a;
  }
#pragma unroll
  for (int ct = 0; ct < 4; ct++)
#pragma unroll
    for (int j = 0; j < 4; j++) {
      int i0 = 16 * wv + quad * 4 + j;
      int j0 = ct * 16 + m16;
      float v = acc[ct][j] * scale + ((addI && i0 == j0) ? 1.0f : 0.0f);
      int idx = transposeStore ? (j0 * SPH + i0) : (i0 * SPH + j0);
      store_split(Ch, Cl, idx, v);
    }
}

// Squaring with max-normalization (A symmetric -> A^2). Internal barrier.
static __device__ __forceinline__ void mm_sq_norm_bf(
    const unsigned short* __restrict__ Ah, const unsigned short* __restrict__ Al,
    unsigned short* __restrict__ Ch, unsigned short* __restrict__ Cl,
    int t, float* __restrict__ redm) {
  int wv = t >> 6, l = t & 63;
  int m16 = l & 15, quad = l >> 4;
  int abase = (16 * wv + m16) * SPH + quad * 8;
  bf8t ah0 = *(const bf8t*)(Ah + abase);
  bf8t ah1 = *(const bf8t*)(Ah + abase + 32);
  bf8t al0 = *(const bf8t*)(Al + abase);
  bf8t al1 = *(const bf8t*)(Al + abase + 32);
  f4t acc[4];
#pragma unroll
  for (int ct = 0; ct < 4; ct++) {
    int bbase = (ct * 16 + m16) * SPH + quad * 8;
    bf8t bh0 = *(const bf8t*)(Ah + bbase);
    bf8t bh1 = *(const bf8t*)(Ah + bbase + 32);
    bf8t bl0 = *(const bf8t*)(Al + bbase);
    bf8t bl1 = *(const bf8t*)(Al + bbase + 32);
    f4t a = (f4t){0.f, 0.f, 0.f, 0.f};
    a = __builtin_amdgcn_mfma_f32_16x16x32_bf16(al0, bh0, a, 0, 0, 0);
    a = __builtin_amdgcn_mfma_f32_16x16x32_bf16(ah0, bl0, a, 0, 0, 0);
    a = __builtin_amdgcn_mfma_f32_16x16x32_bf16(ah0, bh0, a, 0, 0, 0);
    a = __builtin_amdgcn_mfma_f32_16x16x32_bf16(al1, bh1, a, 0, 0, 0);
    a = __builtin_amdgcn_mfma_f32_16x16x32_bf16(ah1, bl1, a, 0, 0, 0);
    a = __builtin_amdgcn_mfma_f32_16x16x32_bf16(ah1, bh1, a, 0, 0, 0);
    acc[ct] = a;
  }
  float mx = 0.f;
#pragma unroll
  for (int ct = 0; ct < 4; ct++)
#pragma unroll
    for (int j = 0; j < 4; j++) mx = fmaxf(mx, fabsf(acc[ct][j]));
#pragma unroll
  for (int m = 1; m < 64; m <<= 1) mx = fmaxf(mx, __shfl_xor(mx, m, 64));
  if (l == 0) redm[wv] = mx;
  __syncthreads();
  float gmx = fmaxf(fmaxf(redm[0], redm[1]), fmaxf(redm[2], redm[3]));
  float sc = 1.0f / fmaxf(gmx, 1e-30f);
#pragma unroll
  for (int ct = 0; ct < 4; ct++)
#pragma unroll
    for (int j = 0; j < 4; j++) {
      int idx = (16 * wv + quad * 4 + j) * SPH + ct * 16 + m16;
      store_split(Ch, Cl, idx, acc[ct][j] * sc);
    }
}

// Gram via MFMA: G = Ag * Ag^T (Ag 64 x ncols row-major f32 global), staged
// into Sh/Sl (split at staging).
static __device__ __forceinline__ void gram_mfma_bf(
    const float* __restrict__ Ag, int ncols,
    unsigned short* __restrict__ Sh, unsigned short* __restrict__ Sl,
    unsigned short* __restrict__ Gh, unsigned short* __restrict__ Gl, int t) {
  int wv = t >> 6, l = t & 63;
  int m16 = l & 15, quad = l >> 4;
  f4t acc[4];
#pragma unroll
  for (int ct = 0; ct < 4; ct++) acc[ct] = (f4t){0.f, 0.f, 0.f, 0.f};
  for (int cc = 0; cc < ncols; cc += 64) {
    if (cc) __syncthreads();
    for (int i = t; i < 1024; i += 256) {
      int r = i >> 4, qq = i & 15;
      float4 v = *(const float4*)(Ag + (size_t)r * ncols + cc + 4 * qq);
      int o = r * SPH + 4 * qq;
      store_split(Sh, Sl, o + 0, v.x);
      store_split(Sh, Sl, o + 1, v.y);
      store_split(Sh, Sl, o + 2, v.z);
      store_split(Sh, Sl, o + 3, v.w);
    }
    __syncthreads();
    int abase = (16 * wv + m16) * SPH + quad * 8;
    bf8t ah0 = *(const bf8t*)(Sh + abase);
    bf8t ah1 = *(const bf8t*)(Sh + abase + 32);
    bf8t al0 = *(const bf8t*)(Sl + abase);
    bf8t al1 = *(const bf8t*)(Sl + abase + 32);
#pragma unroll
    for (int ct = 0; ct < 4; ct++) {
      int bbase = (ct * 16 + m16) * SPH + quad * 8;
      bf8t bh0 = *(const bf8t*)(Sh + bbase);
      bf8t bh1 = *(const bf8t*)(Sh + bbase + 32);
      bf8t bl0 = *(const bf8t*)(Sl + bbase);
      bf8t bl1 = *(const bf8t*)(Sl + bbase + 32);
      f4t a = acc[ct];
      a = __builtin_amdgcn_mfma_f32_16x16x32_bf16(al0, bh0, a, 0, 0, 0);
      a = __builtin_amdgcn_mfma_f32_16x16x32_bf16(ah0, bl0, a, 0, 0, 0);
      a = __builtin_amdgcn_mfma_f32_16x16x32_bf16(ah0, bh0, a, 0, 0, 0);
      a = __builtin_amdgcn_mfma_f32_16x16x32_bf16(al1, bh1, a, 0, 0, 0);
      a = __builtin_amdgcn_mfma_f32_16x16x32_bf16(ah1, bl1, a, 0, 0, 0);
      a = __builtin_amdgcn_mfma_f32_16x16x32_bf16(ah1, bh1, a, 0, 0, 0);
      acc[ct] = a;
    }
  }
  __syncthreads();
#pragma unroll
  for (int ct = 0; ct < 4; ct++)
#pragma unroll
    for (int j = 0; j < 4; j++) {
      int idx = (16 * wv + quad * 4 + j) * SPH + ct * 16 + m16;
      store_split(Gh, Gl, idx, acc[ct][j]);
    }
}

// Single-wave power iteration + Rayleigh; rows reconstructed hi+lo (err ~2^-16).
static __device__ __forceinline__ float power_rayleigh_bf(
    const unsigned short* __restrict__ Sh, const unsigned short* __restrict__ Sl,
    const unsigned short* __restrict__ Gh, const unsigned short* __restrict__ Gl,
    int iters, int i) {
  float row[64];
#pragma unroll
  for (int j = 0; j < 16; j++) {
    ushort4 h = *(const ushort4*)(Sh + i * SPH + 4 * j);
    ushort4 lo = *(const ushort4*)(Sl + i * SPH + 4 * j);
    row[4 * j + 0] = bf2f(h.x) + bf2f(lo.x);
    row[4 * j + 1] = bf2f(h.y) + bf2f(lo.y);
    row[4 * j + 2] = bf2f(h.z) + bf2f(lo.z);
    row[4 * j + 3] = bf2f(h.w) + bf2f(lo.w);
  }
  float v = 1.0f + 0.3f * sinf(7.0f * (float)(i + 1));
  for (int it = 0; it < iters; it++) {
    float u0 = 0.f, u1 = 0.f, u2 = 0.f, u3 = 0.f;
#pragma unroll
    for (int j = 0; j < 16; j++) {
      u0 += row[4 * j + 0] * __shfl(v, 4 * j + 0, 64);
      u1 += row[4 * j + 1] * __shfl(v, 4 * j + 1, 64);
      u2 += row[4 * j + 2] * __shfl(v, 4 * j + 2, 64);
      u3 += row[4 * j + 3] * __shfl(v, 4 * j + 3, 64);
    }
    float u = (u0 + u1) + (u2 + u3);
    float ss = u * u;
#pragma unroll
    for (int m = 1; m < 64; m <<= 1) ss += __shfl_xor(ss, m, 64);
    v = u * rsqrtf(fmaxf(ss, 1e-30f));
  }
  float rowg[64];
#pragma unroll
  for (int j = 0; j < 16; j++) {
    ushort4 h = *(const ushort4*)(Gh + i * SPH + 4 * j);
    ushort4 lo = *(const ushort4*)(Gl + i * SPH + 4 * j);
    rowg[4 * j + 0] = bf2f(h.x) + bf2f(lo.x);
    rowg[4 * j + 1] = bf2f(h.y) + bf2f(lo.y);
    rowg[4 * j + 2] = bf2f(h.z) + bf2f(lo.z);
    rowg[4 * j + 3] = bf2f(h.w) + bf2f(lo.w);
  }
  float u0 = 0.f, u1 = 0.f, u2 = 0.f, u3 = 0.f;
#pragma unroll
  for (int j = 0; j < 16; j++) {
    u0 += rowg[4 * j + 0] * __shfl(v, 4 * j + 0, 64);
    u1 += rowg[4 * j + 1] * __shfl(v, 4 * j + 1, 64);
    u2 += rowg[4 * j + 2] * __shfl(v, 4 * j + 2, 64);
    u3 += rowg[4 * j + 3] * __shfl(v, 4 * j + 3, 64);
  }
  float u = (u0 + u1) + (u2 + u3);
  float d = v * u;
#pragma unroll
  for (int m = 1; m < 64; m <<= 1) d += __shfl_xor(d, m, 64);
  return d;
}

// ---------------------------------------------------------------------------
// Fused spectral norms + lip: grid 130. v2: bf16 hi/lo-resident LDS
// (all matrices __align__(16): bf8t/ushort4 reinterpret-loads require it).
// ---------------------------------------------------------------------------
__global__ __launch_bounds__(256) void speclip_kernel(
    const float* __restrict__ w1, const float* __restrict__ w2,
    const float* __restrict__ gaw, float* __restrict__ invsig1,
    float* __restrict__ invsig2, float* __restrict__ lipv) {
  __shared__ __align__(16) unsigned short Sah[64 * SPH], Sal[64 * SPH];
  __shared__ __align__(16) unsigned short Sbh[64 * SPH], Sbl[64 * SPH];
  __shared__ __align__(16) unsigned short Gh[64 * SPH], Gl[64 * SPH];
  __shared__ float redm[4];
  int t = threadIdx.x;
  int blk = blockIdx.x;
  if (blk < 128) {
    int n = blk & 63;
    const float* A = (blk < 64) ? (w1 + (size_t)n * 4096) : (w2 + (size_t)n * 16384);
    int ncols = (blk < 64) ? 64 : 256;
    gram_mfma_bf(A, ncols, Sah, Sal, Gh, Gl, t);       // G = A A^T
    __syncthreads();
    mm_mfma_bf(Gh, Gl, Gh, Gl, Sah, Sal, t, 1.f, 0, 0); // G^2 -> Sa
    __syncthreads();
    mm_sq_norm_bf(Sah, Sal, Sbh, Sbl, t, redm); __syncthreads(); // G^4   -> Sb
    mm_sq_norm_bf(Sbh, Sbl, Sah, Sal, t, redm); __syncthreads(); // G^8   -> Sa
    mm_sq_norm_bf(Sah, Sal, Sbh, Sbl, t, redm); __syncthreads(); // G^16  -> Sb
    mm_sq_norm_bf(Sbh, Sbl, Sah, Sal, t, redm); __syncthreads(); // G^32  -> Sa
    mm_sq_norm_bf(Sah, Sal, Sbh, Sbl, t, redm); __syncthreads(); // G^64  -> Sb
    mm_sq_norm_bf(Sbh, Sbl, Sah, Sal, t, redm); __syncthreads(); // G^128 -> Sa
    if (t < 64) {
      float d = power_rayleigh_bf(Sah, Sal, Gh, Gl, 2, t);
      if (t == 0) {
        float sg = sqrtf(fmaxf(d, 0.f));
        float inv = 1.0f / fmaxf(sg, 1e-6f);
        if (blk < 64) invsig1[n] = inv; else invsig2[n] = inv;
      }
    }
  } else {
    int l = blk - 128;
    const float* Wb = gaw + (size_t)l * 8192;
    for (int i = t; i < 1024; i += 256) {
      int r = i >> 4, qq = i & 15;
      float4 va = *(const float4*)(Wb + r * 64 + 4 * qq);
      float4 vb = *(const float4*)(Wb + 4096 + r * 64 + 4 * qq);
      int o = r * SPH + 4 * qq;
      store_split(Sah, Sal, o + 0, va.x);
      store_split(Sah, Sal, o + 1, va.y);
      store_split(Sah, Sal, o + 2, va.z);
      store_split(Sah, Sal, o + 3, va.w);
      store_split(Sbh, Sbl, o + 0, vb.x);
      store_split(Sbh, Sbl, o + 1, vb.y);
      store_split(Sbh, Sbl, o + 2, vb.z);
      store_split(Sbh, Sbl, o + 3, vb.w);
    }
    __syncthreads();
    mm_mfma_bf(Sah, Sal, Sbh, Sbl, Gh, Gl, t, 0.25f, 1, 1); // Mt -> G
    __syncthreads();
    mm_mfma_bf(Gh, Gl, Gh, Gl, Sah, Sal, t, 1.f, 0, 0);     // M^T M -> Sa
    __syncthreads();
    mm_sq_norm_bf(Sah, Sal, Sbh, Sbl, t, redm); __syncthreads(); // ^2  -> Sb
    mm_sq_norm_bf(Sbh, Sbl, Gh, Gl, t, redm);   __syncthreads(); // ^4  -> G
    mm_sq_norm_bf(Gh, Gl, Sbh, Sbl, t, redm);   __syncthreads(); // ^8  -> Sb
    mm_sq_norm_bf(Sbh, Sbl, Gh, Gl, t, redm);   __syncthreads(); // ^16 -> G
    mm_sq_norm_bf(Gh, Gl, Sbh, Sbl, t, redm);   __syncthreads(); // ^32 -> Sb
    mm_sq_norm_bf(Sbh, Sbl, Gh, Gl, t, redm);   __syncthreads(); // ^64 -> G
    if (t < 64) {
      float d = power_rayleigh_bf(Gh, Gl, Sah, Sal, 2, t);
      if (t == 0) lipv[l] = sqrtf(fmaxf(d, 0.f)) + 5.0f;
    }
  }
}

// ---------------------------------------------------------------------------
// Fused h+conv: h = gelu(fused @ w1n + b1) stays in LDS; x = h @ w2n + b2.
// grid 512 = b*16+ng.
// ---------------------------------------------------------------------------
__global__ __launch_bounds__(256) void hconv_kernel(
    const float* __restrict__ fused, const float* __restrict__ w1,
    const float* __restrict__ b1, const float* __restrict__ invsig1,
    const float* __restrict__ w2, const float* __restrict__ b2,
    const float* __restrict__ invsig2, float* __restrict__ x) {
  __shared__ float fr[256];
  __shared__ float hr[4][64];
  int t = threadIdx.x;
  int blk = blockIdx.x;
  int b = blk >> 4, ng = blk & 15;
  int n0 = ng * 4;
  fr[t] = fused[(size_t)blk * 256 + t];
  __syncthreads();
  {
    int nl = t >> 6, j = t & 63;
    int n = n0 + nl;
    float is1 = invsig1[n];
    const float* fp = fr + nl * 64;
    const float* wp = w1 + (size_t)n * 4096 + j;
    float acc = 0.f;
    for (int i = 0; i < 64; i++) acc += fp[i] * wp[i * 64];
    acc = acc * is1 + b1[n * 64 + j];
    hr[nl][j] = 0.5f * acc * (1.0f + erff(acc * 0.70710678118654752440f));
  }
  __syncthreads();
  const float* w0p = w2 + ((size_t)(n0 + 0) * 64) * 256 + t;
  const float* w1p = w2 + ((size_t)(n0 + 1) * 64) * 256 + t;
  const float* w2p = w2 + ((size_t)(n0 + 2) * 64) * 256 + t;
  const float* w3p = w2 + ((size_t)(n0 + 3) * 64) * 256 + t;
  float a0 = 0.f, a1 = 0.f, a2 = 0.f, a3 = 0.f;
  for (int i = 0; i < 64; i++) {
    a0 += hr[0][i] * w0p[(size_t)i * 256];
    a1 += hr[1][i] * w1p[(size_t)i * 256];
    a2 += hr[2][i] * w2p[(size_t)i * 256];
    a3 += hr[3][i] * w3p[(size_t)i * 256];
  }
  float4 o;
  o.x = a0 * invsig2[n0 + 0] + b2[(n0 + 0) * 256 + t];
  o.y = a1 * invsig2[n0 + 1] + b2[(n0 + 1) * 256 + t];
  o.z = a2 * invsig2[n0 + 2] + b2[(n0 + 2) * 256 + t];
  o.w = a3 * invsig2[n0 + 3] + b2[(n0 + 3) * 256 + t];
  *(float4*)(x + ((size_t)b * 256 + t) * 64 + n0) = o;
}

// ---------------------------------------------------------------------------
// qk v5: MFMA + LDS-staged coalesced uint4 stores.
// ---------------------------------------------------------------------------
__global__ __launch_bounds__(256, 2) void qk_kernel(
    const float* __restrict__ x, const float* __restrict__ eqk,
    unsigned short* __restrict__ qhi, unsigned short* __restrict__ qlo,
    unsigned short* __restrict__ khi, unsigned short* __restrict__ klo) {
  __shared__ __align__(16) unsigned short TH[128 * 72];
  __shared__ __align__(16) unsigned short TL[128 * 72];
  int t = threadIdx.x;
  int blk = blockIdx.x;
  int xcd = blk & 7;
  int y = blk >> 3;
  int rh = y & 1;
  int c = (y >> 1) & 7;
  int b = (y >> 4) * 8 + xcd;
  int wv = t >> 6, l = t & 63;
  int m16 = l & 15, quad = l >> 4;
  int row0 = rh * 128 + wv * 32;

  bf8t ah[2][2], al[2][2];
#pragma unroll
  for (int rt = 0; rt < 2; rt++) {
    const float* xp = x + ((size_t)b * 256 + row0 + rt * 16 + m16) * 64 + quad * 8;
    split8(xp, &ah[rt][0], &al[rt][0]);
    split8(xp + 32, &ah[rt][1], &al[rt][1]);
  }
#pragma unroll
  for (int mat = 0; mat < 2; mat++) {
    const float* Wbase = eqk + ((size_t)(mat * 8 + c) * 64) * 64;
    unsigned short* ohi = mat ? khi : qhi;
    unsigned short* olo = mat ? klo : qlo;
#pragma unroll
    for (int ct = 0; ct < 4; ct++) {
      bf8t bh[2], bl[2];
      const float* wp = Wbase + (size_t)(ct * 16 + m16) * 64 + quad * 8;
      split8(wp, &bh[0], &bl[0]);
      split8(wp + 32, &bh[1], &bl[1]);
#pragma unroll
      for (int rt = 0; rt < 2; rt++) {
        f4t a = (f4t){0.f, 0.f, 0.f, 0.f};
        a = __builtin_amdgcn_mfma_f32_16x16x32_bf16(al[rt][0], bh[0], a, 0, 0, 0);
        a = __builtin_amdgcn_mfma_f32_16x16x32_bf16(ah[rt][0], bl[0], a, 0, 0, 0);
        a = __builtin_amdgcn_mfma_f32_16x16x32_bf16(ah[rt][0], bh[0], a, 0, 0, 0);
        a = __builtin_amdgcn_mfma_f32_16x16x32_bf16(al[rt][1], bh[1], a, 0, 0, 0);
        a = __builtin_amdgcn_mfma_f32_16x16x32_bf16(ah[rt][1], bl[1], a, 0, 0, 0);
        a = __builtin_amdgcn_mfma_f32_16x16x32_bf16(ah[rt][1], bh[1], a, 0, 0, 0);
#pragma unroll
        for (int j = 0; j < 4; j++) {
          int lr = (wv << 5) + rt * 16 + quad * 4 + j;   // 0..127 local row
          int f = ct * 16 + m16;
          float v = a[j];
          unsigned short hh = f2bf(v);
          TH[lr * 72 + f] = hh;
          TL[lr * 72 + f] = f2bf(v - bf2f(hh));
        }
      }
    }
    __syncthreads();
    // coalesced store: 128 rows x 64 ushorts contiguous in global
    size_t gbase = ((size_t)b * 8 + c) * 16384 + (size_t)rh * 8192;
#pragma unroll
    for (int k = 0; k < 4; k++) {
      int i = t + k * 256;           // uint4 index 0..1023
      int r = i >> 3, f8 = i & 7;
      *(uint4*)(ohi + gbase + (size_t)i * 8) = *(const uint4*)(TH + r * 72 + f8 * 8);
      *(uint4*)(olo + gbase + (size_t)i * 8) = *(const uint4*)(TL + r * 72 + f8 * 8);
    }
    if (mat == 0) __syncthreads();
  }
}

// ---------------------------------------------------------------------------
// Fused attn v9 (R2-proven, 60 VGPR): K hi/lo for both c's staged in LDS
// (64 KB, MFMA-fragment order), 2 phases of 8 tiles.
// ---------------------------------------------------------------------------
__global__ __launch_bounds__(512, 4) void attn_kernel(
    const unsigned short* __restrict__ qhi, const unsigned short* __restrict__ qlo,
    const unsigned short* __restrict__ khi, const unsigned short* __restrict__ klo,
    float* __restrict__ seP, float* __restrict__ mxb, float* __restrict__ rzb) {
  __shared__ uint4 KS4[4096];                    // 64 KB
  unsigned short* KS = (unsigned short*)KS4;
  float* sE = (float*)KS4;                       // alias (32*260 floats, 33 KB)
  int t = threadIdx.x;
  int blk = blockIdx.x;
  int xcd = blk & 7;
  int y = blk >> 3;
  int b = xcd * 4 + (y & 3);
  int cg = (y >> 2) & 3;
  int ng = y >> 4;
  int wave = t >> 6;       // 0..7
  int ci = wave >> 2;      // 0,1: which c of the cg pair
  int wv = wave & 3;       // 16-row sub-tile
  int l = t & 63;
  int m16 = l & 15, quad = l >> 4;
  int n0w = ng * 64 + wv * 16;
  int c = cg * 2 + ci;

  size_t slA = ((size_t)b * 8 + cg * 2) * 16384;   // cc=0 slice (ushort units)
  size_t slB = slA + 16384;                        // cc=1 slice
  size_t sl = ((size_t)b * 8 + c) * 16384;

  // Q fragments (global, once)
  const bf8t* qh = (const bf8t*)(qhi + sl + (size_t)(n0w + m16) * 64 + quad * 8);
  const bf8t* ql = (const bf8t*)(qlo + sl + (size_t)(n0w + m16) * 64 + quad * 8);
  bf8t ah0 = qh[0], ah1 = qh[4];
  bf8t al0 = ql[0], al1 = ql[4];

  // staging decode (entry e = it*512 + t)
  int sthalf = (t >> 6) & 1;
  int tllo = (t >> 7) & 3;
  int srcbase = tllo * 1024 + m16 * 64 + sthalf * 32 + quad * 8;  // ushort
  int dstbase = t * 8;                                            // ushort

  int lane8 = (quad * 16 + m16) * 8;
  int cbase = ci * 16384;

  f4t acc[16];
#pragma unroll
  for (int mt = 0; mt < 16; mt++) acc[mt] = (f4t){0.f, 0.f, 0.f, 0.f};

#pragma unroll
  for (int p = 0; p < 2; p++) {
    if (p) __syncthreads();               // all waves done reading previous phase
    int pb = srcbase + p * 8192;
#pragma unroll
    for (int g = 0; g < 2; g++) {         // g = cc
      const unsigned short* bhp = khi + (g ? slB : slA) + pb;
      const unsigned short* blp = klo + (g ? slB : slA) + pb;
      uint4 v0 = *(const uint4*)(bhp);
      uint4 v1 = *(const uint4*)(bhp + 4096);
      uint4 v2 = *(const uint4*)(blp);
      uint4 v3 = *(const uint4*)(blp + 4096);
      *(uint4*)(KS + dstbase + (g * 4 + 0) * 4096) = v0;
      *(uint4*)(KS + dstbase + (g * 4 + 1) * 4096) = v1;
      *(uint4*)(KS + dstbase + (g * 4 + 2) * 4096) = v2;
      *(uint4*)(KS + dstbase + (g * 4 + 3) * 4096) = v3;
    }
    __syncthreads();                      // staging visible
#pragma unroll
    for (int tl = 0; tl < 8; tl++) {
      int mt = p * 8 + tl;
      int tb = cbase + tl * 1024 + lane8;
      bf8t bh0 = *(const bf8t*)(KS + tb);
      bf8t bh1 = *(const bf8t*)(KS + tb + 512);
      bf8t bl0 = *(const bf8t*)(KS + tb + 8192);
      bf8t bl1 = *(const bf8t*)(KS + tb + 8704);
      f4t a = acc[mt];
      a = __builtin_amdgcn_mfma_f32_16x16x32_bf16(al0, bh0, a, 0, 0, 0);
      a = __builtin_amdgcn_mfma_f32_16x16x32_bf16(ah0, bl0, a, 0, 0, 0);
      a = __builtin_amdgcn_mfma_f32_16x16x32_bf16(ah0, bh0, a, 0, 0, 0);
      a = __builtin_amdgcn_mfma_f32_16x16x32_bf16(al1, bh1, a, 0, 0, 0);
      a = __builtin_amdgcn_mfma_f32_16x16x32_bf16(ah1, bl1, a, 0, 0, 0);
      a = __builtin_amdgcn_mfma_f32_16x16x32_bf16(ah1, bh1, a, 0, 0, 0);
      acc[mt] = a;
    }
  }
  // softmax per output row j; converts acc in place to probs (e * 1/z)
#pragma unroll
  for (int j = 0; j < 4; j++) {
    float mx = -FLT_MAX;
#pragma unroll
    for (int mt = 0; mt < 16; mt++) mx = fmaxf(mx, acc[mt][j]);
    mx = fmaxf(mx, __shfl_xor(mx, 1, 64));
    mx = fmaxf(mx, __shfl_xor(mx, 2, 64));
    mx = fmaxf(mx, __shfl_xor(mx, 4, 64));
    mx = fmaxf(mx, __shfl_xor(mx, 8, 64));
    float mxl = mx * 0.125f;
    float z = 0.f;
#pragma unroll
    for (int mt = 0; mt < 16; mt++) {
      float e = expf(acc[mt][j] * 0.125f - mxl);
      acc[mt][j] = e;
      z += e;
    }
    z += __shfl_xor(z, 1, 64);
    z += __shfl_xor(z, 2, 64);
    z += __shfl_xor(z, 4, 64);
    z += __shfl_xor(z, 8, 64);
    int n = n0w + quad * 4 + j;
    if (m16 == 0) {
      mxb[((size_t)b * 8 + c) * 256 + n] = mxl;
      rzb[((size_t)b * 8 + c) * 256 + n] = z;
    }
    float zi = 1.0f / z;
#pragma unroll
    for (int mt = 0; mt < 16; mt++) acc[mt][j] *= zi;
  }
  __syncthreads();   // KS reads done everywhere; sE alias now safe
  // cross-c combine + coalesced seP store, two 32-row passes through LDS
  for (int half = 0; half < 2; half++) {
    if (ci == 0 && (wv >> 1) == half) {
      int r0 = (wv & 1) * 16;
#pragma unroll
      for (int mt = 0; mt < 16; mt++)
#pragma unroll
        for (int j = 0; j < 4; j++)
          sE[(r0 + quad * 4 + j) * 260 + mt * 16 + m16] = acc[mt][j];
    }
    __syncthreads();
    if (ci == 1 && (wv >> 1) == half) {
      int r0 = (wv & 1) * 16;
#pragma unroll
      for (int mt = 0; mt < 16; mt++)
#pragma unroll
        for (int j = 0; j < 4; j++)
          sE[(r0 + quad * 4 + j) * 260 + mt * 16 + m16] += acc[mt][j];
    }
    __syncthreads();
    float4* dst4 = (float4*)(seP + (((size_t)cg * 32 + b) * 256 + ng * 64 + half * 32) * 256);
    for (int i = t; i < 2048; i += 512) {
      int r = i >> 6, c4 = i & 63;
      dst4[i] = *(const float4*)(sE + r * 260 + c4 * 4);
    }
    if (half == 0) __syncthreads();
  }
}

// ---------------------------------------------------------------------------
// Top-6 selection (R7-measured v1: grid 128, colsum fold).
// ---------------------------------------------------------------------------
__global__ __launch_bounds__(256) void topsel_kernel(
    const float* __restrict__ seP, int* __restrict__ idx7,
    float* __restrict__ colsum) {
  __shared__ float seL[64 * 260];
  __shared__ float cv[64][24];
  __shared__ int cidx[64][24];
  int t = threadIdx.x;
  int b = blockIdx.x >> 2, rg = blockIdx.x & 3;
  int n0 = rg * 64;
  for (int i = t; i < 512; i += 256)
    colsum[(size_t)b * 2048 + rg * 512 + i] = 0.f;
  const float* s0 = seP + ((size_t)b * 256 + n0) * 256;
  const float* s1 = seP + ((size_t)(32 + b) * 256 + n0) * 256;
  const float* s2 = seP + ((size_t)(64 + b) * 256 + n0) * 256;
  const float* s3 = seP + ((size_t)(96 + b) * 256 + n0) * 256;
  for (int i = t; i < 4096; i += 256) {
    int m4 = i & 63, r = i >> 6;
    float4 v0 = ((const float4*)(s0 + (size_t)r * 256))[m4];
    float4 v1 = ((const float4*)(s1 + (size_t)r * 256))[m4];
    float4 v2 = ((const float4*)(s2 + (size_t)r * 256))[m4];
    float4 v3 = ((const float4*)(s3 + (size_t)r * 256))[m4];
    float4 s;
    s.x = (v0.x + v1.x) + (v2.x + v3.x);
    s.y = (v0.y + v1.y) + (v2.y + v3.y);
    s.z = (v0.z + v1.z) + (v2.z + v3.z);
    s.w = (v0.w + v1.w) + (v2.w + v3.w);
    *(float4*)(seL + r * 260 + m4 * 4) = s;
  }
  __syncthreads();
  {
    int r = t >> 2, qtr = t & 3;
    float tv[6]; int ti[6];
#pragma unroll
    for (int s = 0; s < 6; s++) { tv[s] = -FLT_MAX; ti[s] = 1 << 30; }
    for (int i = 0; i < 64; i++) {
      int m = 4 * i + qtr;
      float val = seL[r * 260 + m];
      if (val > tv[5]) {
        tv[5] = val; ti[5] = m;
#pragma unroll
        for (int s = 5; s > 0; s--) {
          if (tv[s] > tv[s - 1]) {
            float tmv = tv[s]; tv[s] = tv[s - 1]; tv[s - 1] = tmv;
            int tmi = ti[s]; ti[s] = ti[s - 1]; ti[s - 1] = tmi;
          }
        }
      }
    }
#pragma unroll
    for (int s = 0; s < 6; s++) { cv[r][qtr * 6 + s] = tv[s]; cidx[r][qtr * 6 + s] = ti[s]; }
  }
  __syncthreads();
  if (t < 64) {
    int r = t, n = n0 + r;
    int sel[7];
    for (int round = 0; round < 6; round++) {
      float best = -FLT_MAX; int bi = 1 << 30, bs = 0;
      for (int j = 0; j < 24; j++) {
        float v = cv[r][j]; int id = cidx[r][j];
        if (v > best || (v == best && id < bi)) { best = v; bi = id; bs = j; }
      }
      sel[round] = bi;
      cv[r][bs] = -FLT_MAX;
    }
    bool dup = false;
#pragma unroll
    for (int j = 0; j < 6; j++) dup = dup || (sel[j] == n);
    sel[6] = dup ? -1 : n;
#pragma unroll
    for (int j = 0; j < 7; j++) idx7[((size_t)b * 256 + n) * 7 + j] = sel[j];
  }
}

// ---------------------------------------------------------------------------
// nr values: recompute <=7 attn entries from the stored bf16 3-term split
// (consistent with attn's mxb/rzb), row-normalize, atomic colsum.
// ---------------------------------------------------------------------------
__global__ __launch_bounds__(256) void nr_kernel(
    const unsigned short* __restrict__ qhi, const unsigned short* __restrict__ qlo,
    const unsigned short* __restrict__ khi, const unsigned short* __restrict__ klo,
    const float* __restrict__ mxb, const float* __restrict__ rzb,
    const int* __restrict__ idx7, float* __restrict__ nrv,
    float* __restrict__ colsum) {
  __shared__ int idxs[7];
  __shared__ float attL[56];
  int t = threadIdx.x;
  int b = blockIdx.x >> 8, n = blockIdx.x & 255;
  if (t < 7) idxs[t] = idx7[(size_t)blockIdx.x * 7 + t];
  __syncthreads();
  int task = t >> 2, l4 = t & 3;
  if (task < 56) {
    int c = task / 7, j = task - c * 7;
    int d = idxs[j];
    float s = 0.f;
    if (d >= 0) {
      size_t qo = (((size_t)b * 8 + c) * 256 + n) * 64 + l4 * 16;
      size_t ko = (((size_t)b * 8 + c) * 256 + d) * 64 + l4 * 16;
      const uint4* qh4 = (const uint4*)(qhi + qo);
      const uint4* ql4 = (const uint4*)(qlo + qo);
      const uint4* kh4 = (const uint4*)(khi + ko);
      const uint4* kl4 = (const uint4*)(klo + ko);
#pragma unroll
      for (int g = 0; g < 2; g++) {
        uint4 uqh = qh4[g], uql = ql4[g], ukh = kh4[g], ukl = kl4[g];
        s += dot3_pair(uqh.x, uql.x, ukh.x, ukl.x);
        s += dot3_pair(uqh.y, uql.y, ukh.y, ukl.y);
        s += dot3_pair(uqh.z, uql.z, ukh.z, ukl.z);
        s += dot3_pair(uqh.w, uql.w, ukh.w, ukl.w);
      }
    }
    s += __shfl_xor(s, 1, 64);
    s += __shfl_xor(s, 2, 64);
    if (l4 == 0) {
      float att = 0.f;
      if (d >= 0) {
        float logit = s * 0.125f;
        att = expf(logit - mxb[((size_t)b * 8 + c) * 256 + n]) / rzb[((size_t)b * 8 + c) * 256 + n];
      }
      attL[task] = att;
    }
  }
  __syncthreads();
  if (t < 8) {
    float rs = 0.f;
#pragma unroll
    for (int j = 0; j < 7; j++) rs += attL[t * 7 + j];
    float ri = 1.0f / (rs + 1e-6f);
#pragma unroll
    for (int j = 0; j < 7; j++) {
      float nv = attL[t * 7 + j] * ri;
      nrv[(((size_t)b * 8 + t) * 256 + n) * 7 + j] = nv;
      int d = idxs[j];
      if (d >= 0) atomicAdd(&colsum[((size_t)b * 8 + t) * 256 + d], nv);
    }
  }
}

// ---------------------------------------------------------------------------
// edge v2 (R6-proven): grid 2048, branchless gather, 28 KB LDS.
// ---------------------------------------------------------------------------
__global__ __launch_bounds__(256, 5) void edge_kernel(
    const int* __restrict__ idx7, const float* __restrict__ nrv,
    const float* __restrict__ colsum, unsigned short* __restrict__ edge) {
  __shared__ unsigned short ncT[256 * 32];   // 16 KB
  __shared__ short idxL[256 * 8];            // 4 KB
  __shared__ float nrvL[256 * 8];            // 8 KB
  int t = threadIdx.x;
  int blk = blockIdx.x;
  int b = blk >> 6, c = (blk >> 3) & 7, mq = blk & 7;
  int m0 = mq * 32;
  for (int i = t; i < 4096; i += 256) ((unsigned int*)ncT)[i] = 0u;
  for (int i = t; i < 2048; i += 256) {
    int r = i >> 3, j = i & 7;
    if (j < 7) {
      idxL[i] = (short)idx7[(size_t)b * 1792 + r * 7 + j];
      nrvL[i] = nrv[((size_t)b * 8 + c) * 1792 + r * 7 + j];
    } else {
      idxL[i] = -1;
      nrvL[i] = 0.f;
    }
  }
  __syncthreads();
  for (int i = t; i < 224; i += 256) {
    int mi = i / 7, j = i - mi * 7;
    int m = m0 + mi;
    int d = idxL[m * 8 + j];
    if (d >= 0) {
      float cs = colsum[((size_t)b * 8 + c) * 256 + d];
      ncT[d * 32 + mi] = f2bf(nrvL[m * 8 + j] / (cs + 1e-6f));
    }
  }
  __syncthreads();
  int wv = t >> 6, l = t & 63;
  int qtr = l >> 4, p = l & 15;
  const unsigned int* ncP = (const unsigned int*)ncT;
  unsigned int* eb = (unsigned int*)(edge + (((size_t)b * 8 + c) * 256) * 256);
#pragma unroll 4
  for (int nn = 0; nn < 16; nn++) {
    int n = nn * 16 + wv * 4 + qtr;
    int4 iv = *(const int4*)(idxL + n * 8);
    float4 w0 = *(const float4*)(nrvL + n * 8);
    float4 w1 = *(const float4*)(nrvL + n * 8 + 4);
    // branchless: d=-1 -> row 255, weight is exactly 0
    unsigned p0 = ncP[(iv.x & 255) * 16 + p];
    unsigned p1 = ncP[((iv.x >> 16) & 255) * 16 + p];
    unsigned p2 = ncP[(iv.y & 255) * 16 + p];
    unsigned p3 = ncP[((iv.y >> 16) & 255) * 16 + p];
    unsigned p4 = ncP[(iv.z & 255) * 16 + p];
    unsigned p5 = ncP[((iv.z >> 16) & 255) * 16 + p];
    unsigned p6 = ncP[(iv.w & 255) * 16 + p];
    float a0 = w0.x * bf2f_lo(p0) + w0.y * bf2f_lo(p1) + w0.z * bf2f_lo(p2)
             + w0.w * bf2f_lo(p3) + w1.x * bf2f_lo(p4) + w1.y * bf2f_lo(p5)
             + w1.z * bf2f_lo(p6);
    float a1 = w0.x * bf2f_hi(p0) + w0.y * bf2f_hi(p1) + w0.z * bf2f_hi(p2)
             + w0.w * bf2f_hi(p3) + w1.x * bf2f_hi(p4) + w1.y * bf2f_hi(p5)
             + w1.z * bf2f_hi(p6);
    unsigned int packo = (unsigned int)f2bf(a0) | ((unsigned int)f2bf(a1) << 16);
    eb[n * 128 + (m0 >> 1) + p] = packo;
  }
}

// ---------------------------------------------------------------------------
// qkx v3: fused xs + qg + kg (row-major). grid 128.
// ---------------------------------------------------------------------------
static __device__ __forceinline__ float selu1(float v) {
  float e = (v > 0.f) ? v : expm1f(v);
  return 1.0f / (1.0f + expf(-e));
}
__global__ __launch_bounds__(256, 1) void qkx_kernel(
    const float* __restrict__ x, const float* __restrict__ gaw,
    const float* __restrict__ gab, int l, float* __restrict__ xs,
    float* __restrict__ qg, float* __restrict__ kg) {
  __shared__ float xsL[64 * 64];
  int t = threadIdx.x;
  int b = blockIdx.x >> 2, nt = blockIdx.x & 3;
  int f = t & 63, part = t >> 6;
  float wq[64], wk[64];
  const float4* Wq4 = (const float4*)(gaw + (size_t)l * 8192 + f * 64);
  const float4* Wk4 = (const float4*)(gaw + (size_t)l * 8192 + (64 + f) * 64);
#pragma unroll
  for (int j = 0; j < 16; j++) {
    float4 aa = Wq4[j];
    wq[4 * j + 0] = aa.x; wq[4 * j + 1] = aa.y; wq[4 * j + 2] = aa.z; wq[4 * j + 3] = aa.w;
    float4 bb = Wk4[j];
    wk[4 * j + 0] = bb.x; wk[4 * j + 1] = bb.y; wk[4 * j + 2] = bb.z; wk[4 * j + 3] = bb.w;
  }
  float bq = gab[l * 128 + f], bk = gab[l * 128 + 64 + f];
  for (int i = t; i < 1024; i += 256) {
    float4 v = ((const float4*)(x + ((size_t)b * 256 + nt * 64) * 64))[i];
    float4 o;
    o.x = selu1(v.x); o.y = selu1(v.y); o.z = selu1(v.z); o.w = selu1(v.w);
    ((float4*)xsL)[i] = o;
    ((float4*)(xs + ((size_t)b * 256 + nt * 64) * 64))[i] = o;
  }
  __syncthreads();
  for (int i = 0; i < 16; i++) {
    int nl = part * 16 + i;
    const float4* xr = (const float4*)(xsL + nl * 64);
    float aq = 0.f, ak = 0.f;
#pragma unroll
    for (int j = 0; j < 16; j++) {
      float4 v = xr[j];
      aq += v.x * wq[4 * j] + v.y * wq[4 * j + 1] + v.z * wq[4 * j + 2] + v.w * wq[4 * j + 3];
      ak += v.x * wk[4 * j] + v.y * wk[4 * j + 1] + v.z * wk[4 * j + 2] + v.w * wk[4 * j + 3];
    }
    int n = nt * 64 + nl;
    qg[((size_t)b * 256 + n) * 64 + f] = aq + bq;
    kg[((size_t)b * 256 + n) * 64 + f] = ak + bk;
  }
}

// ---------------------------------------------------------------------------
// upd v2: ga_attn fused in.
// ---------------------------------------------------------------------------
__global__ __launch_bounds__(256) void upd_kernel(
    const float* __restrict__ qg, const float* __restrict__ kg,
    const unsigned short* __restrict__ edge,
    const float* __restrict__ xs, const float* __restrict__ gaww,
    const float* __restrict__ lipv, int l, float* __restrict__ x) {
  __shared__ float tt[4][8][260];
  __shared__ float ne3[4][256];
  __shared__ float parts[4][4][64];
  __shared__ float dred[32][8];
  __shared__ float dinv[4][8];
  __shared__ float wcL[8];
  __shared__ float lipi;
  __shared__ float qgL[4][64];
  __shared__ float rred[2][4][4];   // [max/sum][row][wave]
  int t = threadIdx.x;
  int b = blockIdx.x >> 6, nq = blockIdx.x & 63;
  int n0 = nq * 4;
  int wave = t >> 6;
  if (t == 0) {
    float s = 0.f;
    float wtmp[8];
    for (int c = 0; c < 8; c++) { wtmp[c] = gaww[l * 8 + c]; s += wtmp[c]; }
    for (int c = 0; c < 8; c++) wcL[c] = wtmp[c] / s;
    lipi = 1.0f / lipv[l];
  }
  {
    int r = t >> 6, f = t & 63;
    qgL[r][f] = qg[((size_t)b * 256 + n0 + r) * 64 + f];
  }
  __syncthreads();
  // ---- inline ga_attn: thread t = column m; 4 rows ----
  float d0 = 0.f, d1 = 0.f, d2 = 0.f, d3 = 0.f;
  {
    const float4* kr = (const float4*)(kg + ((size_t)b * 256 + t) * 64);
#pragma unroll
    for (int j = 0; j < 16; j++) {
      float4 kv = kr[j];
      float4 q0 = ((const float4*)qgL[0])[j];
      float4 q1 = ((const float4*)qgL[1])[j];
      float4 q2 = ((const float4*)qgL[2])[j];
      float4 q3 = ((const float4*)qgL[3])[j];
      d0 += q0.x * kv.x + q0.y * kv.y + q0.z * kv.z + q0.w * kv.w;
      d1 += q1.x * kv.x + q1.y * kv.y + q1.z * kv.z + q1.w * kv.w;
      d2 += q2.x * kv.x + q2.y * kv.y + q2.z * kv.z + q2.w * kv.w;
      d3 += q3.x * kv.x + q3.y * kv.y + q3.z * kv.z + q3.w * kv.w;
    }
  }
  d0 *= 0.125f; d1 *= 0.125f; d2 *= 0.125f; d3 *= 0.125f;
  {
    float m0 = d0, m1 = d1, m2 = d2, m3 = d3;
#pragma unroll
    for (int mm = 1; mm < 64; mm <<= 1) {
      m0 = fmaxf(m0, __shfl_xor(m0, mm, 64));
      m1 = fmaxf(m1, __shfl_xor(m1, mm, 64));
      m2 = fmaxf(m2, __shfl_xor(m2, mm, 64));
      m3 = fmaxf(m3, __shfl_xor(m3, mm, 64));
    }
    if ((t & 63) == 0) {
      rred[0][0][wave] = m0; rred[0][1][wave] = m1;
      rred[0][2][wave] = m2; rred[0][3][wave] = m3;
    }
  }
  __syncthreads();
  {
    float g0 = fmaxf(fmaxf(rred[0][0][0], rred[0][0][1]), fmaxf(rred[0][0][2], rred[0][0][3]));
    float g1 = fmaxf(fmaxf(rred[0][1][0], rred[0][1][1]), fmaxf(rred[0][1][2], rred[0][1][3]));
    float g2 = fmaxf(fmaxf(rred[0][2][0], rred[0][2][1]), fmaxf(rred[0][2][2], rred[0][2][3]));
    float g3 = fmaxf(fmaxf(rred[0][3][0], rred[0][3][1]), fmaxf(rred[0][3][2], rred[0][3][3]));
    d0 = expf(d0 - g0); d1 = expf(d1 - g1); d2 = expf(d2 - g2); d3 = expf(d3 - g3);
    float s0 = d0, s1 = d1, s2 = d2, s3 = d3;
#pragma unroll
    for (int mm = 1; mm < 64; mm <<= 1) {
      s0 += __shfl_xor(s0, mm, 64);
      s1 += __shfl_xor(s1, mm, 64);
      s2 += __shfl_xor(s2, mm, 64);
      s3 += __shfl_xor(s3, mm, 64);
    }
    if ((t & 63) == 0) {
      rred[1][0][wave] = s0; rred[1][1][wave] = s1;
      rred[1][2][wave] = s2; rred[1][3][wave] = s3;
    }
  }
  __syncthreads();
  float av[4];
  {
    float z0 = (rred[1][0][0] + rred[1][0][1]) + (rred[1][0][2] + rred[1][0][3]);
    float z1 = (rred[1][1][0] + rred[1][1][1]) + (rred[1][1][2] + rred[1][1][3]);
    float z2 = (rred[1][2][0] + rred[1][2][1]) + (rred[1][2][2] + rred[1][2][3]);
    float z3 = (rred[1][3][0] + rred[1][3][1]) + (rred[1][3][2] + rred[1][3][3]);
    av[0] = d0 / z0; av[1] = d1 / z1; av[2] = d2 / z2; av[3] = d3 / z3;
  }
  // ---- ne pipeline ----
#pragma unroll
  for (int r = 0; r < 4; r++) {
#pragma unroll
    for (int c = 0; c < 8; c++)
      tt[r][c][t] = av[r] * bf2f(edge[(((size_t)b * 8 + c) * 256 + n0 + r) * 256 + t]);
  }
  __syncthreads();
  {
    int rc = t >> 3, i = t & 7;
    int r = rc >> 3, c = rc & 7;
    float p = 0.f;
#pragma unroll
    for (int kq = 0; kq < 32; kq++) p += tt[r][c][i + 8 * kq];
    dred[rc][i] = p;
  }
  __syncthreads();
  if (t < 32) {
    float s = 0.f;
#pragma unroll
    for (int i = 0; i < 8; i++) s += dred[t][i];
    dinv[t >> 3][t & 7] = 1.0f / (s + 1e-6f);
  }
  __syncthreads();
#pragma unroll
  for (int r = 0; r < 4; r++) {
    float s = 0.f;
#pragma unroll
    for (int c = 0; c < 8; c++) s += wcL[c] * tt[r][c][t] * dinv[r][c];
    ne3[r][t] = s;
  }
  __syncthreads();
  {
    int f = t & 63, part = t >> 6;
    float a0 = 0.f, a1 = 0.f, a2 = 0.f, a3 = 0.f;
    for (int mm = 0; mm < 64; mm++) {
      int m = part * 64 + mm;
      float xv = xs[((size_t)b * 256 + m) * 64 + f];
      a0 += ne3[0][m] * xv;
      a1 += ne3[1][m] * xv;
      a2 += ne3[2][m] * xv;
      a3 += ne3[3][m] * xv;
    }
    parts[0][part][f] = a0;
    parts[1][part][f] = a1;
    parts[2][part][f] = a2;
    parts[3][part][f] = a3;
  }
  __syncthreads();
  {
    int r = t >> 6, f = t & 63;
    float dx = parts[r][0][f] + parts[r][1][f] + parts[r][2][f] + parts[r][3][f];
    x[((size_t)b * 256 + n0 + r) * 64 + f] += dx * lipi;
  }
}

// ---------------------------------------------------------------------------
extern "C" void kernel_launch(void* const* d_in, const int* in_sizes, int n_in,
                              void* d_out, int out_size, void* d_ws, size_t ws_size,
                              hipStream_t stream) {
  (void)in_sizes; (void)n_in; (void)out_size; (void)ws_size;
  const float* fused = (const float*)d_in[0];
  const float* w1 = (const float*)d_in[1];
  const float* b1 = (const float*)d_in[2];
  const float* w2 = (const float*)d_in[3];
  const float* b2 = (const float*)d_in[4];
  const float* eqk = (const float*)d_in[5];
  const float* gaw = (const float*)d_in[6];
  const float* gab = (const float*)d_in[7];
  const float* gaww = (const float*)d_in[8];
  float* x = (float*)d_out;  // x lives in d_out (B,ND,NF)=(32,256,64); fully overwritten.
  char* ws = (char*)d_ws;
  size_t off = 0;
  auto alloc = [&](size_t bytes) -> char* {
    char* p = ws + off;
    off += (bytes + 1023) & ~(size_t)1023;
    return p;
  };
  float* invsig1 = (float*)alloc(64 * 4);
  float* invsig2 = (float*)alloc(64 * 4);
  float* lipv = (float*)alloc(2 * 4);
  unsigned short* qhi = (unsigned short*)alloc((size_t)32 * 8 * 256 * 64 * 2);
  unsigned short* qlo = (unsigned short*)alloc((size_t)32 * 8 * 256 * 64 * 2);
  unsigned short* khi = (unsigned short*)alloc((size_t)32 * 8 * 256 * 64 * 2);
  unsigned short* klo = (unsigned short*)alloc((size_t)32 * 8 * 256 * 64 * 2);
  // seP (4 partials, 33.5 MB) aliases edge (33.5 MB): seP dead after topsel.
  char* sep_edge = alloc((size_t)4 * 32 * 256 * 256 * 4);
  float* seP = (float*)sep_edge;
  unsigned short* edge = (unsigned short*)sep_edge;
  float* mxb = (float*)alloc((size_t)65536 * 4);
  float* rzb = (float*)alloc((size_t)65536 * 4);
  int* idx7 = (int*)alloc((size_t)8192 * 7 * 4);
  float* nrv = (float*)alloc((size_t)65536 * 7 * 4);
  float* colsum = (float*)alloc((size_t)65536 * 4);
  float* xs = (float*)alloc((size_t)524288 * 4);
  float* qg = (float*)alloc((size_t)524288 * 4);
  float* kg = (float*)alloc((size_t)524288 * 4);

  speclip_kernel<<<130, 256, 0, stream>>>(w1, w2, gaw, invsig1, invsig2, lipv);
  hconv_kernel<<<512, 256, 0, stream>>>(fused, w1, b1, invsig1, w2, b2, invsig2, x);
  qk_kernel<<<512, 256, 0, stream>>>(x, eqk, qhi, qlo, khi, klo);
  attn_kernel<<<512, 512, 0, stream>>>(qhi, qlo, khi, klo, seP, mxb, rzb);
  topsel_kernel<<<128, 256, 0, stream>>>(seP, idx7, colsum);
  nr_kernel<<<8192, 256, 0, stream>>>(qhi, qlo, khi, klo, mxb, rzb, idx7, nrv, colsum);
  edge_kernel<<<2048, 256, 0, stream>>>(idx7, nrv, colsum, edge);
  for (int l = 0; l < 2; l++) {
    qkx_kernel<<<128, 256, 0, stream>>>(x, gaw, gab, l, xs, qg, kg);
    upd_kernel<<<2048, 256, 0, stream>>>(qg, kg, edge, xs, gaww, lipv, l, x);
  }
}

// Round 11
// 330.076 us; speedup vs baseline: 1.0666x; 1.0268x over previous
//
#include <hip/hip_runtime.h>
#include <float.h>
#include <math.h>

// Problem constants: B=32, NF=64, FD=64, ND=256, C=8, K=6, L=2, scale=1/8.

typedef short bf8t __attribute__((ext_vector_type(8)));   // 8 bf16 in 4 VGPRs
typedef float f4t __attribute__((ext_vector_type(4)));

static __device__ __forceinline__ unsigned short f2bf(float x) {
  union { float f; unsigned u; } v; v.f = x;
  unsigned r = (v.u + 0x7FFFu + ((v.u >> 16) & 1u)) >> 16;
  return (unsigned short)r;
}
static __device__ __forceinline__ float bf2f(unsigned short s) {
  union { unsigned u; float f; } v; v.u = ((unsigned)s) << 16; return v.f;
}
static __device__ __forceinline__ float bf2f_lo(unsigned u) {
  union { unsigned u; float f; } v; v.u = u << 16; return v.f;
}
static __device__ __forceinline__ float bf2f_hi(unsigned u) {
  union { unsigned u; float f; } v; v.u = u & 0xFFFF0000u; return v.f;
}
// 2 packed elems of the 3-term split dot: qh*(kh+kl) + ql*kh
static __device__ __forceinline__ float dot3_pair(unsigned uqh, unsigned uql,
                                                  unsigned ukh, unsigned ukl) {
  float s = bf2f_lo(uqh) * (bf2f_lo(ukh) + bf2f_lo(ukl)) + bf2f_lo(uql) * bf2f_lo(ukh);
  s += bf2f_hi(uqh) * (bf2f_hi(ukh) + bf2f_hi(ukl)) + bf2f_hi(uql) * bf2f_hi(ukh);
  return s;
}
// split 8 fp32 into hi/lo bf16 fragments
static __device__ __forceinline__ void split8(const float* __restrict__ p,
                                              bf8t* hi, bf8t* lo) {
  float4 v0 = *(const float4*)(p);
  float4 v1 = *(const float4*)(p + 4);
  float v[8] = {v0.x, v0.y, v0.z, v0.w, v1.x, v1.y, v1.z, v1.w};
#pragma unroll
  for (int j = 0; j < 8; j++) {
    unsigned short h = f2bf(v[j]);
    (*hi)[j] = (short)h;
    (*lo)[j] = (short)f2bf(v[j] - bf2f(h));
  }
}
// split one f32 into hi/lo bf16 stored at idx
static __device__ __forceinline__ void store_split(
    unsigned short* __restrict__ h, unsigned short* __restrict__ lo,
    int idx, float v) {
  unsigned short hh = f2bf(v);
  h[idx] = hh;
  lo[idx] = f2bf(v - bf2f(hh));
}

#define SPH 72    // LDS ushort row stride for speclip bf16-resident matrices

// ---------------------------------------------------------------------------
// speclip v2 helpers: matrices live in LDS as bf16 hi/lo (split ONCE at write).
// ---------------------------------------------------------------------------
static __device__ __forceinline__ void mm_mfma_bf(
    const unsigned short* __restrict__ Ah, const unsigned short* __restrict__ Al,
    const unsigned short* __restrict__ Bh, const unsigned short* __restrict__ Bl,
    unsigned short* __restrict__ Ch, unsigned short* __restrict__ Cl,
    int t, float scale, int addI, int transposeStore) {
  int wv = t >> 6, l = t & 63;
  int m16 = l & 15, quad = l >> 4;
  int abase = (16 * wv + m16) * SPH + quad * 8;
  bf8t ah0 = *(const bf8t*)(Ah + abase);
  bf8t ah1 = *(const bf8t*)(Ah + abase + 32);
  bf8t al0 = *(const bf8t*)(Al + abase);
  bf8t al1 = *(const bf8t*)(Al + abase + 32);
  f4t acc[4];
#pragma unroll
  for (int ct = 0; ct < 4; ct++) {
    int bbase = (ct * 16 + m16) * SPH + quad * 8;
    bf8t bh0 = *(const bf8t*)(Bh + bbase);
    bf8t bh1 = *(const bf8t*)(Bh + bbase + 32);
    bf8t bl0 = *(const bf8t*)(Bl + bbase);
    bf8t bl1 = *(const bf8t*)(Bl + bbase + 32);
    f4t a = (f4t){0.f, 0.f, 0.f, 0.f};
    a = __builtin_amdgcn_mfma_f32_16x16x32_bf16(al0, bh0, a, 0, 0, 0);
    a = __builtin_amdgcn_mfma_f32_16x16x32_bf16(ah0, bl0, a, 0, 0, 0);
    a = __builtin_amdgcn_mfma_f32_16x16x32_bf16(ah0, bh0, a, 0, 0, 0);
    a = __builtin_amdgcn_mfma_f32_16x16x32_bf16(al1, bh1, a, 0, 0, 0);
    a = __builtin_amdgcn_mfma_f32_16x16x32_bf16(ah1, bl1, a, 0, 0, 0);
    a = __builtin_amdgcn_mfma_f32_16x16x32_bf16(ah1, bh1, a, 0, 0, 0);
    acc[ct] = a;
  }
#pragma unroll
  for (int ct = 0; ct < 4; ct++)
#pragma unroll
    for (int j = 0; j < 4; j++) {
      int i0 = 16 * wv + quad * 4 + j;
      int j0 = ct * 16 + m16;
      float v = acc[ct][j] * scale + ((addI && i0 == j0) ? 1.0f : 0.0f);
      int idx = transposeStore ? (j0 * SPH + i0) : (i0 * SPH + j0);
      store_split(Ch, Cl, idx, v);
    }
}

// Squaring with max-normalization (A symmetric -> A^2). Internal barrier.
static __device__ __forceinline__ void mm_sq_norm_bf(
    const unsigned short* __restrict__ Ah, const unsigned short* __restrict__ Al,
    unsigned short* __restrict__ Ch, unsigned short* __restrict__ Cl,
    int t, float* __restrict__ redm) {
  int wv = t >> 6, l = t & 63;
  int m16 = l & 15, quad = l >> 4;
  int abase = (16 * wv + m16) * SPH + quad * 8;
  bf8t ah0 = *(const bf8t*)(Ah + abase);
  bf8t ah1 = *(const bf8t*)(Ah + abase + 32);
  bf8t al0 = *(const bf8t*)(Al + abase);
  bf8t al1 = *(const bf8t*)(Al + abase + 32);
  f4t acc[4];
#pragma unroll
  for (int ct = 0; ct < 4; ct++) {
    int bbase = (ct * 16 + m16) * SPH + quad * 8;
    bf8t bh0 = *(const bf8t*)(Ah + bbase);
    bf8t bh1 = *(const bf8t*)(Ah + bbase + 32);
    bf8t bl0 = *(const bf8t*)(Al + bbase);
    bf8t bl1 = *(const bf8t*)(Al + bbase + 32);
    f4t a = (f4t){0.f, 0.f, 0.f, 0.f};
    a = __builtin_amdgcn_mfma_f32_16x16x32_bf16(al0, bh0, a, 0, 0, 0);
    a = __builtin_amdgcn_mfma_f32_16x16x32_bf16(ah0, bl0, a, 0, 0, 0);
    a = __builtin_amdgcn_mfma_f32_16x16x32_bf16(ah0, bh0, a, 0, 0, 0);
    a = __builtin_amdgcn_mfma_f32_16x16x32_bf16(al1, bh1, a, 0, 0, 0);
    a = __builtin_amdgcn_mfma_f32_16x16x32_bf16(ah1, bl1, a, 0, 0, 0);
    a = __builtin_amdgcn_mfma_f32_16x16x32_bf16(ah1, bh1, a, 0, 0, 0);
    acc[ct] = a;
  }
  float mx = 0.f;
#pragma unroll
  for (int ct = 0; ct < 4; ct++)
#pragma unroll
    for (int j = 0; j < 4; j++) mx = fmaxf(mx, fabsf(acc[ct][j]));
#pragma unroll
  for (int m = 1; m < 64; m <<= 1) mx = fmaxf(mx, __shfl_xor(mx, m, 64));
  if (l == 0) redm[wv] = mx;
  __syncthreads();
  float gmx = fmaxf(fmaxf(redm[0], redm[1]), fmaxf(redm[2], redm[3]));
  float sc = 1.0f / fmaxf(gmx, 1e-30f);
#pragma unroll
  for (int ct = 0; ct < 4; ct++)
#pragma unroll
    for (int j = 0; j < 4; j++) {
      int idx = (16 * wv + quad * 4 + j) * SPH + ct * 16 + m16;
      store_split(Ch, Cl, idx, acc[ct][j] * sc);
    }
}

// Gram via MFMA: G = Ag * Ag^T (Ag 64 x ncols row-major f32 global), staged
// into Sh/Sl (split at staging).
static __device__ __forceinline__ void gram_mfma_bf(
    const float* __restrict__ Ag, int ncols,
    unsigned short* __restrict__ Sh, unsigned short* __restrict__ Sl,
    unsigned short* __restrict__ Gh, unsigned short* __restrict__ Gl, int t) {
  int wv = t >> 6, l = t & 63;
  int m16 = l & 15, quad = l >> 4;
  f4t acc[4];
#pragma unroll
  for (int ct = 0; ct < 4; ct++) acc[ct] = (f4t){0.f, 0.f, 0.f, 0.f};
  for (int cc = 0; cc < ncols; cc += 64) {
    if (cc) __syncthreads();
    for (int i = t; i < 1024; i += 256) {
      int r = i >> 4, qq = i & 15;
      float4 v = *(const float4*)(Ag + (size_t)r * ncols + cc + 4 * qq);
      int o = r * SPH + 4 * qq;
      store_split(Sh, Sl, o + 0, v.x);
      store_split(Sh, Sl, o + 1, v.y);
      store_split(Sh, Sl, o + 2, v.z);
      store_split(Sh, Sl, o + 3, v.w);
    }
    __syncthreads();
    int abase = (16 * wv + m16) * SPH + quad * 8;
    bf8t ah0 = *(const bf8t*)(Sh + abase);
    bf8t ah1 = *(const bf8t*)(Sh + abase + 32);
    bf8t al0 = *(const bf8t*)(Sl + abase);
    bf8t al1 = *(const bf8t*)(Sl + abase + 32);
#pragma unroll
    for (int ct = 0; ct < 4; ct++) {
      int bbase = (ct * 16 + m16) * SPH + quad * 8;
      bf8t bh0 = *(const bf8t*)(Sh + bbase);
      bf8t bh1 = *(const bf8t*)(Sh + bbase + 32);
      bf8t bl0 = *(const bf8t*)(Sl + bbase);
      bf8t bl1 = *(const bf8t*)(Sl + bbase + 32);
      f4t a = acc[ct];
      a = __builtin_amdgcn_mfma_f32_16x16x32_bf16(al0, bh0, a, 0, 0, 0);
      a = __builtin_amdgcn_mfma_f32_16x16x32_bf16(ah0, bl0, a, 0, 0, 0);
      a = __builtin_amdgcn_mfma_f32_16x16x32_bf16(ah0, bh0, a, 0, 0, 0);
      a = __builtin_amdgcn_mfma_f32_16x16x32_bf16(al1, bh1, a, 0, 0, 0);
      a = __builtin_amdgcn_mfma_f32_16x16x32_bf16(ah1, bl1, a, 0, 0, 0);
      a = __builtin_amdgcn_mfma_f32_16x16x32_bf16(ah1, bh1, a, 0, 0, 0);
      acc[ct] = a;
    }
  }
  __syncthreads();
#pragma unroll
  for (int ct = 0; ct < 4; ct++)
#pragma unroll
    for (int j = 0; j < 4; j++) {
      int idx = (16 * wv + quad * 4 + j) * SPH + ct * 16 + m16;
      store_split(Gh, Gl, idx, acc[ct][j]);
    }
}

// Single-wave power iteration + Rayleigh; rows reconstructed hi+lo (err ~2^-16).
static __device__ __forceinline__ float power_rayleigh_bf(
    const unsigned short* __restrict__ Sh, const unsigned short* __restrict__ Sl,
    const unsigned short* __restrict__ Gh, const unsigned short* __restrict__ Gl,
    int iters, int i) {
  float row[64];
#pragma unroll
  for (int j = 0; j < 16; j++) {
    ushort4 h = *(const ushort4*)(Sh + i * SPH + 4 * j);
    ushort4 lo = *(const ushort4*)(Sl + i * SPH + 4 * j);
    row[4 * j + 0] = bf2f(h.x) + bf2f(lo.x);
    row[4 * j + 1] = bf2f(h.y) + bf2f(lo.y);
    row[4 * j + 2] = bf2f(h.z) + bf2f(lo.z);
    row[4 * j + 3] = bf2f(h.w) + bf2f(lo.w);
  }
  float v = 1.0f + 0.3f * sinf(7.0f * (float)(i + 1));
  for (int it = 0; it < iters; it++) {
    float u0 = 0.f, u1 = 0.f, u2 = 0.f, u3 = 0.f;
#pragma unroll
    for (int j = 0; j < 16; j++) {
      u0 += row[4 * j + 0] * __shfl(v, 4 * j + 0, 64);
      u1 += row[4 * j + 1] * __shfl(v, 4 * j + 1, 64);
      u2 += row[4 * j + 2] * __shfl(v, 4 * j + 2, 64);
      u3 += row[4 * j + 3] * __shfl(v, 4 * j + 3, 64);
    }
    float u = (u0 + u1) + (u2 + u3);
    float ss = u * u;
#pragma unroll
    for (int m = 1; m < 64; m <<= 1) ss += __shfl_xor(ss, m, 64);
    v = u * rsqrtf(fmaxf(ss, 1e-30f));
  }
  float rowg[64];
#pragma unroll
  for (int j = 0; j < 16; j++) {
    ushort4 h = *(const ushort4*)(Gh + i * SPH + 4 * j);
    ushort4 lo = *(const ushort4*)(Gl + i * SPH + 4 * j);
    rowg[4 * j + 0] = bf2f(h.x) + bf2f(lo.x);
    rowg[4 * j + 1] = bf2f(h.y) + bf2f(lo.y);
    rowg[4 * j + 2] = bf2f(h.z) + bf2f(lo.z);
    rowg[4 * j + 3] = bf2f(h.w) + bf2f(lo.w);
  }
  float u0 = 0.f, u1 = 0.f, u2 = 0.f, u3 = 0.f;
#pragma unroll
  for (int j = 0; j < 16; j++) {
    u0 += rowg[4 * j + 0] * __shfl(v, 4 * j + 0, 64);
    u1 += rowg[4 * j + 1] * __shfl(v, 4 * j + 1, 64);
    u2 += rowg[4 * j + 2] * __shfl(v, 4 * j + 2, 64);
    u3 += rowg[4 * j + 3] * __shfl(v, 4 * j + 3, 64);
  }
  float u = (u0 + u1) + (u2 + u3);
  float d = v * u;
#pragma unroll
  for (int m = 1; m < 64; m <<= 1) d += __shfl_xor(d, m, 64);
  return d;
}

// ---------------------------------------------------------------------------
// Fused spectral norms + lip: grid 130. v2: bf16 hi/lo-resident LDS.
// ---------------------------------------------------------------------------
__global__ __launch_bounds__(256) void speclip_kernel(
    const float* __restrict__ w1, const float* __restrict__ w2,
    const float* __restrict__ gaw, float* __restrict__ invsig1,
    float* __restrict__ invsig2, float* __restrict__ lipv) {
  __shared__ __align__(16) unsigned short Sah[64 * SPH], Sal[64 * SPH];
  __shared__ __align__(16) unsigned short Sbh[64 * SPH], Sbl[64 * SPH];
  __shared__ __align__(16) unsigned short Gh[64 * SPH], Gl[64 * SPH];
  __shared__ float redm[4];
  int t = threadIdx.x;
  int blk = blockIdx.x;
  if (blk < 128) {
    int n = blk & 63;
    const float* A = (blk < 64) ? (w1 + (size_t)n * 4096) : (w2 + (size_t)n * 16384);
    int ncols = (blk < 64) ? 64 : 256;
    gram_mfma_bf(A, ncols, Sah, Sal, Gh, Gl, t);       // G = A A^T
    __syncthreads();
    mm_mfma_bf(Gh, Gl, Gh, Gl, Sah, Sal, t, 1.f, 0, 0); // G^2 -> Sa
    __syncthreads();
    mm_sq_norm_bf(Sah, Sal, Sbh, Sbl, t, redm); __syncthreads(); // G^4   -> Sb
    mm_sq_norm_bf(Sbh, Sbl, Sah, Sal, t, redm); __syncthreads(); // G^8   -> Sa
    mm_sq_norm_bf(Sah, Sal, Sbh, Sbl, t, redm); __syncthreads(); // G^16  -> Sb
    mm_sq_norm_bf(Sbh, Sbl, Sah, Sal, t, redm); __syncthreads(); // G^32  -> Sa
    mm_sq_norm_bf(Sah, Sal, Sbh, Sbl, t, redm); __syncthreads(); // G^64  -> Sb
    mm_sq_norm_bf(Sbh, Sbl, Sah, Sal, t, redm); __syncthreads(); // G^128 -> Sa
    if (t < 64) {
      float d = power_rayleigh_bf(Sah, Sal, Gh, Gl, 2, t);
      if (t == 0) {
        float sg = sqrtf(fmaxf(d, 0.f));
        float inv = 1.0f / fmaxf(sg, 1e-6f);
        if (blk < 64) invsig1[n] = inv; else invsig2[n] = inv;
      }
    }
  } else {
    int l = blk - 128;
    const float* Wb = gaw + (size_t)l * 8192;
    for (int i = t; i < 1024; i += 256) {
      int r = i >> 4, qq = i & 15;
      float4 va = *(const float4*)(Wb + r * 64 + 4 * qq);
      float4 vb = *(const float4*)(Wb + 4096 + r * 64 + 4 * qq);
      int o = r * SPH + 4 * qq;
      store_split(Sah, Sal, o + 0, va.x);
      store_split(Sah, Sal, o + 1, va.y);
      store_split(Sah, Sal, o + 2, va.z);
      store_split(Sah, Sal, o + 3, va.w);
      store_split(Sbh, Sbl, o + 0, vb.x);
      store_split(Sbh, Sbl, o + 1, vb.y);
      store_split(Sbh, Sbl, o + 2, vb.z);
      store_split(Sbh, Sbl, o + 3, vb.w);
    }
    __syncthreads();
    mm_mfma_bf(Sah, Sal, Sbh, Sbl, Gh, Gl, t, 0.25f, 1, 1); // Mt -> G
    __syncthreads();
    mm_mfma_bf(Gh, Gl, Gh, Gl, Sah, Sal, t, 1.f, 0, 0);     // M^T M -> Sa
    __syncthreads();
    mm_sq_norm_bf(Sah, Sal, Sbh, Sbl, t, redm); __syncthreads(); // ^2  -> Sb
    mm_sq_norm_bf(Sbh, Sbl, Gh, Gl, t, redm);   __syncthreads(); // ^4  -> G
    mm_sq_norm_bf(Gh, Gl, Sbh, Sbl, t, redm);   __syncthreads(); // ^8  -> Sb
    mm_sq_norm_bf(Sbh, Sbl, Gh, Gl, t, redm);   __syncthreads(); // ^16 -> G
    mm_sq_norm_bf(Gh, Gl, Sbh, Sbl, t, redm);   __syncthreads(); // ^32 -> Sb
    mm_sq_norm_bf(Sbh, Sbl, Gh, Gl, t, redm);   __syncthreads(); // ^64 -> G
    if (t < 64) {
      float d = power_rayleigh_bf(Gh, Gl, Sah, Sal, 2, t);
      if (t == 0) lipv[l] = sqrtf(fmaxf(d, 0.f)) + 5.0f;
    }
  }
}

// ---------------------------------------------------------------------------
// Fused h+conv: h = gelu(fused @ w1n + b1) stays in LDS; x = h @ w2n + b2.
// grid 512 = b*16+ng.
// ---------------------------------------------------------------------------
__global__ __launch_bounds__(256) void hconv_kernel(
    const float* __restrict__ fused, const float* __restrict__ w1,
    const float* __restrict__ b1, const float* __restrict__ invsig1,
    const float* __restrict__ w2, const float* __restrict__ b2,
    const float* __restrict__ invsig2, float* __restrict__ x) {
  __shared__ float fr[256];
  __shared__ float hr[4][64];
  int t = threadIdx.x;
  int blk = blockIdx.x;
  int b = blk >> 4, ng = blk & 15;
  int n0 = ng * 4;
  fr[t] = fused[(size_t)blk * 256 + t];
  __syncthreads();
  {
    int nl = t >> 6, j = t & 63;
    int n = n0 + nl;
    float is1 = invsig1[n];
    const float* fp = fr + nl * 64;
    const float* wp = w1 + (size_t)n * 4096 + j;
    float acc = 0.f;
    for (int i = 0; i < 64; i++) acc += fp[i] * wp[i * 64];
    acc = acc * is1 + b1[n * 64 + j];
    hr[nl][j] = 0.5f * acc * (1.0f + erff(acc * 0.70710678118654752440f));
  }
  __syncthreads();
  const float* w0p = w2 + ((size_t)(n0 + 0) * 64) * 256 + t;
  const float* w1p = w2 + ((size_t)(n0 + 1) * 64) * 256 + t;
  const float* w2p = w2 + ((size_t)(n0 + 2) * 64) * 256 + t;
  const float* w3p = w2 + ((size_t)(n0 + 3) * 64) * 256 + t;
  float a0 = 0.f, a1 = 0.f, a2 = 0.f, a3 = 0.f;
  for (int i = 0; i < 64; i++) {
    a0 += hr[0][i] * w0p[(size_t)i * 256];
    a1 += hr[1][i] * w1p[(size_t)i * 256];
    a2 += hr[2][i] * w2p[(size_t)i * 256];
    a3 += hr[3][i] * w3p[(size_t)i * 256];
  }
  float4 o;
  o.x = a0 * invsig2[n0 + 0] + b2[(n0 + 0) * 256 + t];
  o.y = a1 * invsig2[n0 + 1] + b2[(n0 + 1) * 256 + t];
  o.z = a2 * invsig2[n0 + 2] + b2[(n0 + 2) * 256 + t];
  o.w = a3 * invsig2[n0 + 3] + b2[(n0 + 3) * 256 + t];
  *(float4*)(x + ((size_t)b * 256 + t) * 64 + n0) = o;
}

// ---------------------------------------------------------------------------
// qk v5: MFMA + LDS-staged coalesced uint4 stores.
// ---------------------------------------------------------------------------
__global__ __launch_bounds__(256, 2) void qk_kernel(
    const float* __restrict__ x, const float* __restrict__ eqk,
    unsigned short* __restrict__ qhi, unsigned short* __restrict__ qlo,
    unsigned short* __restrict__ khi, unsigned short* __restrict__ klo) {
  __shared__ __align__(16) unsigned short TH[128 * 72];
  __shared__ __align__(16) unsigned short TL[128 * 72];
  int t = threadIdx.x;
  int blk = blockIdx.x;
  int xcd = blk & 7;
  int y = blk >> 3;
  int rh = y & 1;
  int c = (y >> 1) & 7;
  int b = (y >> 4) * 8 + xcd;
  int wv = t >> 6, l = t & 63;
  int m16 = l & 15, quad = l >> 4;
  int row0 = rh * 128 + wv * 32;

  bf8t ah[2][2], al[2][2];
#pragma unroll
  for (int rt = 0; rt < 2; rt++) {
    const float* xp = x + ((size_t)b * 256 + row0 + rt * 16 + m16) * 64 + quad * 8;
    split8(xp, &ah[rt][0], &al[rt][0]);
    split8(xp + 32, &ah[rt][1], &al[rt][1]);
  }
#pragma unroll
  for (int mat = 0; mat < 2; mat++) {
    const float* Wbase = eqk + ((size_t)(mat * 8 + c) * 64) * 64;
    unsigned short* ohi = mat ? khi : qhi;
    unsigned short* olo = mat ? klo : qlo;
#pragma unroll
    for (int ct = 0; ct < 4; ct++) {
      bf8t bh[2], bl[2];
      const float* wp = Wbase + (size_t)(ct * 16 + m16) * 64 + quad * 8;
      split8(wp, &bh[0], &bl[0]);
      split8(wp + 32, &bh[1], &bl[1]);
#pragma unroll
      for (int rt = 0; rt < 2; rt++) {
        f4t a = (f4t){0.f, 0.f, 0.f, 0.f};
        a = __builtin_amdgcn_mfma_f32_16x16x32_bf16(al[rt][0], bh[0], a, 0, 0, 0);
        a = __builtin_amdgcn_mfma_f32_16x16x32_bf16(ah[rt][0], bl[0], a, 0, 0, 0);
        a = __builtin_amdgcn_mfma_f32_16x16x32_bf16(ah[rt][0], bh[0], a, 0, 0, 0);
        a = __builtin_amdgcn_mfma_f32_16x16x32_bf16(al[rt][1], bh[1], a, 0, 0, 0);
        a = __builtin_amdgcn_mfma_f32_16x16x32_bf16(ah[rt][1], bl[1], a, 0, 0, 0);
        a = __builtin_amdgcn_mfma_f32_16x16x32_bf16(ah[rt][1], bh[1], a, 0, 0, 0);
#pragma unroll
        for (int j = 0; j < 4; j++) {
          int lr = (wv << 5) + rt * 16 + quad * 4 + j;   // 0..127 local row
          int f = ct * 16 + m16;
          float v = a[j];
          unsigned short hh = f2bf(v);
          TH[lr * 72 + f] = hh;
          TL[lr * 72 + f] = f2bf(v - bf2f(hh));
        }
      }
    }
    __syncthreads();
    // coalesced store: 128 rows x 64 ushorts contiguous in global
    size_t gbase = ((size_t)b * 8 + c) * 16384 + (size_t)rh * 8192;
#pragma unroll
    for (int k = 0; k < 4; k++) {
      int i = t + k * 256;           // uint4 index 0..1023
      int r = i >> 3, f8 = i & 7;
      *(uint4*)(ohi + gbase + (size_t)i * 8) = *(const uint4*)(TH + r * 72 + f8 * 8);
      *(uint4*)(olo + gbase + (size_t)i * 8) = *(const uint4*)(TL + r * 72 + f8 * 8);
    }
    if (mat == 0) __syncthreads();
  }
}

// ---------------------------------------------------------------------------
// Fused attn v9 (R2-proven, 60 VGPR): K hi/lo for both c's staged in LDS
// (64 KB, MFMA-fragment order), 2 phases of 8 tiles.
// ---------------------------------------------------------------------------
__global__ __launch_bounds__(512, 4) void attn_kernel(
    const unsigned short* __restrict__ qhi, const unsigned short* __restrict__ qlo,
    const unsigned short* __restrict__ khi, const unsigned short* __restrict__ klo,
    float* __restrict__ seP, float* __restrict__ mxb, float* __restrict__ rzb) {
  __shared__ uint4 KS4[4096];                    // 64 KB
  unsigned short* KS = (unsigned short*)KS4;
  float* sE = (float*)KS4;                       // alias (32*260 floats, 33 KB)
  int t = threadIdx.x;
  int blk = blockIdx.x;
  int xcd = blk & 7;
  int y = blk >> 3;
  int b = xcd * 4 + (y & 3);
  int cg = (y >> 2) & 3;
  int ng = y >> 4;
  int wave = t >> 6;       // 0..7
  int ci = wave >> 2;      // 0,1: which c of the cg pair
  int wv = wave & 3;       // 16-row sub-tile
  int l = t & 63;
  int m16 = l & 15, quad = l >> 4;
  int n0w = ng * 64 + wv * 16;
  int c = cg * 2 + ci;

  size_t slA = ((size_t)b * 8 + cg * 2) * 16384;   // cc=0 slice (ushort units)
  size_t slB = slA + 16384;                        // cc=1 slice
  size_t sl = ((size_t)b * 8 + c) * 16384;

  // Q fragments (global, once)
  const bf8t* qh = (const bf8t*)(qhi + sl + (size_t)(n0w + m16) * 64 + quad * 8);
  const bf8t* ql = (const bf8t*)(qlo + sl + (size_t)(n0w + m16) * 64 + quad * 8);
  bf8t ah0 = qh[0], ah1 = qh[4];
  bf8t al0 = ql[0], al1 = ql[4];

  // staging decode (entry e = it*512 + t)
  int sthalf = (t >> 6) & 1;
  int tllo = (t >> 7) & 3;
  int srcbase = tllo * 1024 + m16 * 64 + sthalf * 32 + quad * 8;  // ushort
  int dstbase = t * 8;                                            // ushort

  int lane8 = (quad * 16 + m16) * 8;
  int cbase = ci * 16384;

  f4t acc[16];
#pragma unroll
  for (int mt = 0; mt < 16; mt++) acc[mt] = (f4t){0.f, 0.f, 0.f, 0.f};

#pragma unroll
  for (int p = 0; p < 2; p++) {
    if (p) __syncthreads();               // all waves done reading previous phase
    int pb = srcbase + p * 8192;
#pragma unroll
    for (int g = 0; g < 2; g++) {         // g = cc
      const unsigned short* bhp = khi + (g ? slB : slA) + pb;
      const unsigned short* blp = klo + (g ? slB : slA) + pb;
      uint4 v0 = *(const uint4*)(bhp);
      uint4 v1 = *(const uint4*)(bhp + 4096);
      uint4 v2 = *(const uint4*)(blp);
      uint4 v3 = *(const uint4*)(blp + 4096);
      *(uint4*)(KS + dstbase + (g * 4 + 0) * 4096) = v0;
      *(uint4*)(KS + dstbase + (g * 4 + 1) * 4096) = v1;
      *(uint4*)(KS + dstbase + (g * 4 + 2) * 4096) = v2;
      *(uint4*)(KS + dstbase + (g * 4 + 3) * 4096) = v3;
    }
    __syncthreads();                      // staging visible
#pragma unroll
    for (int tl = 0; tl < 8; tl++) {
      int mt = p * 8 + tl;
      int tb = cbase + tl * 1024 + lane8;
      bf8t bh0 = *(const bf8t*)(KS + tb);
      bf8t bh1 = *(const bf8t*)(KS + tb + 512);
      bf8t bl0 = *(const bf8t*)(KS + tb + 8192);
      bf8t bl1 = *(const bf8t*)(KS + tb + 8704);
      f4t a = acc[mt];
      a = __builtin_amdgcn_mfma_f32_16x16x32_bf16(al0, bh0, a, 0, 0, 0);
      a = __builtin_amdgcn_mfma_f32_16x16x32_bf16(ah0, bl0, a, 0, 0, 0);
      a = __builtin_amdgcn_mfma_f32_16x16x32_bf16(ah0, bh0, a, 0, 0, 0);
      a = __builtin_amdgcn_mfma_f32_16x16x32_bf16(al1, bh1, a, 0, 0, 0);
      a = __builtin_amdgcn_mfma_f32_16x16x32_bf16(ah1, bl1, a, 0, 0, 0);
      a = __builtin_amdgcn_mfma_f32_16x16x32_bf16(ah1, bh1, a, 0, 0, 0);
      acc[mt] = a;
    }
  }
  // softmax per output row j; converts acc in place to probs (e * 1/z)
#pragma unroll
  for (int j = 0; j < 4; j++) {
    float mx = -FLT_MAX;
#pragma unroll
    for (int mt = 0; mt < 16; mt++) mx = fmaxf(mx, acc[mt][j]);
    mx = fmaxf(mx, __shfl_xor(mx, 1, 64));
    mx = fmaxf(mx, __shfl_xor(mx, 2, 64));
    mx = fmaxf(mx, __shfl_xor(mx, 4, 64));
    mx = fmaxf(mx, __shfl_xor(mx, 8, 64));
    float mxl = mx * 0.125f;
    float z = 0.f;
#pragma unroll
    for (int mt = 0; mt < 16; mt++) {
      float e = expf(acc[mt][j] * 0.125f - mxl);
      acc[mt][j] = e;
      z += e;
    }
    z += __shfl_xor(z, 1, 64);
    z += __shfl_xor(z, 2, 64);
    z += __shfl_xor(z, 4, 64);
    z += __shfl_xor(z, 8, 64);
    int n = n0w + quad * 4 + j;
    if (m16 == 0) {
      mxb[((size_t)b * 8 + c) * 256 + n] = mxl;
      rzb[((size_t)b * 8 + c) * 256 + n] = z;
    }
    float zi = 1.0f / z;
#pragma unroll
    for (int mt = 0; mt < 16; mt++) acc[mt][j] *= zi;
  }
  __syncthreads();   // KS reads done everywhere; sE alias now safe
  // cross-c combine + coalesced seP store, two 32-row passes through LDS
  for (int half = 0; half < 2; half++) {
    if (ci == 0 && (wv >> 1) == half) {
      int r0 = (wv & 1) * 16;
#pragma unroll
      for (int mt = 0; mt < 16; mt++)
#pragma unroll
        for (int j = 0; j < 4; j++)
          sE[(r0 + quad * 4 + j) * 260 + mt * 16 + m16] = acc[mt][j];
    }
    __syncthreads();
    if (ci == 1 && (wv >> 1) == half) {
      int r0 = (wv & 1) * 16;
#pragma unroll
      for (int mt = 0; mt < 16; mt++)
#pragma unroll
        for (int j = 0; j < 4; j++)
          sE[(r0 + quad * 4 + j) * 260 + mt * 16 + m16] += acc[mt][j];
    }
    __syncthreads();
    float4* dst4 = (float4*)(seP + (((size_t)cg * 32 + b) * 256 + ng * 64 + half * 32) * 256);
    for (int i = t; i < 2048; i += 512) {
      int r = i >> 6, c4 = i & 63;
      dst4[i] = *(const float4*)(sE + r * 260 + c4 * 4);
    }
    if (half == 0) __syncthreads();
  }
}

// ---------------------------------------------------------------------------
// Top-6 selection (R7-measured v1: grid 128, colsum fold).
// ---------------------------------------------------------------------------
__global__ __launch_bounds__(256) void topsel_kernel(
    const float* __restrict__ seP, int* __restrict__ idx7,
    float* __restrict__ colsum) {
  __shared__ float seL[64 * 260];
  __shared__ float cv[64][24];
  __shared__ int cidx[64][24];
  int t = threadIdx.x;
  int b = blockIdx.x >> 2, rg = blockIdx.x & 3;
  int n0 = rg * 64;
  for (int i = t; i < 512; i += 256)
    colsum[(size_t)b * 2048 + rg * 512 + i] = 0.f;
  const float* s0 = seP + ((size_t)b * 256 + n0) * 256;
  const float* s1 = seP + ((size_t)(32 + b) * 256 + n0) * 256;
  const float* s2 = seP + ((size_t)(64 + b) * 256 + n0) * 256;
  const float* s3 = seP + ((size_t)(96 + b) * 256 + n0) * 256;
  for (int i = t; i < 4096; i += 256) {
    int m4 = i & 63, r = i >> 6;
    float4 v0 = ((const float4*)(s0 + (size_t)r * 256))[m4];
    float4 v1 = ((const float4*)(s1 + (size_t)r * 256))[m4];
    float4 v2 = ((const float4*)(s2 + (size_t)r * 256))[m4];
    float4 v3 = ((const float4*)(s3 + (size_t)r * 256))[m4];
    float4 s;
    s.x = (v0.x + v1.x) + (v2.x + v3.x);
    s.y = (v0.y + v1.y) + (v2.y + v3.y);
    s.z = (v0.z + v1.z) + (v2.z + v3.z);
    s.w = (v0.w + v1.w) + (v2.w + v3.w);
    *(float4*)(seL + r * 260 + m4 * 4) = s;
  }
  __syncthreads();
  {
    int r = t >> 2, qtr = t & 3;
    float tv[6]; int ti[6];
#pragma unroll
    for (int s = 0; s < 6; s++) { tv[s] = -FLT_MAX; ti[s] = 1 << 30; }
    for (int i = 0; i < 64; i++) {
      int m = 4 * i + qtr;
      float val = seL[r * 260 + m];
      if (val > tv[5]) {
        tv[5] = val; ti[5] = m;
#pragma unroll
        for (int s = 5; s > 0; s--) {
          if (tv[s] > tv[s - 1]) {
            float tmv = tv[s]; tv[s] = tv[s - 1]; tv[s - 1] = tmv;
            int tmi = ti[s]; ti[s] = ti[s - 1]; ti[s - 1] = tmi;
          }
        }
      }
    }
#pragma unroll
    for (int s = 0; s < 6; s++) { cv[r][qtr * 6 + s] = tv[s]; cidx[r][qtr * 6 + s] = ti[s]; }
  }
  __syncthreads();
  if (t < 64) {
    int r = t, n = n0 + r;
    int sel[7];
    for (int round = 0; round < 6; round++) {
      float best = -FLT_MAX; int bi = 1 << 30, bs = 0;
      for (int j = 0; j < 24; j++) {
        float v = cv[r][j]; int id = cidx[r][j];
        if (v > best || (v == best && id < bi)) { best = v; bi = id; bs = j; }
      }
      sel[round] = bi;
      cv[r][bs] = -FLT_MAX;
    }
    bool dup = false;
#pragma unroll
    for (int j = 0; j < 6; j++) dup = dup || (sel[j] == n);
    sel[6] = dup ? -1 : n;
#pragma unroll
    for (int j = 0; j < 7; j++) idx7[((size_t)b * 256 + n) * 7 + j] = sel[j];
  }
}

// ---------------------------------------------------------------------------
// nr v2: grid 1024 = b*32+ng, 8 n per block (was 8192 blocks x 1 n:
// 8/256 threads active in phase 2, 458K global atomics, idx/mxb headers
// re-read 8x). 448 dot tasks in 7 full-width passes; colsum accumulated in
// LDS (csL[8][256], LDS atomics — top-6 d's cluster across neighboring n)
// then sparse-flushed (skip zeros) -> far fewer global atomics + k-row L2
// reuse within block. Per-entry math identical to v1.
// ---------------------------------------------------------------------------
__global__ __launch_bounds__(256) void nr_kernel(
    const unsigned short* __restrict__ qhi, const unsigned short* __restrict__ qlo,
    const unsigned short* __restrict__ khi, const unsigned short* __restrict__ klo,
    const float* __restrict__ mxb, const float* __restrict__ rzb,
    const int* __restrict__ idx7, float* __restrict__ nrv,
    float* __restrict__ colsum) {
  __shared__ short idxs[8][8];     // [nl][j], j<7 valid
  __shared__ float attL[8][64];    // [nl][c*7+j]
  __shared__ float csL[8][256];    // [c][d] block-local colsum
  int t = threadIdx.x;
  int b = blockIdx.x >> 5, ng = blockIdx.x & 31;
  int n0 = ng * 8;
  for (int i = t; i < 2048; i += 256) ((float*)csL)[i] = 0.f;
  if (t < 64) {
    int nl = t >> 3, j = t & 7;
    idxs[nl][j] = (j < 7) ? (short)idx7[((size_t)b * 256 + n0 + nl) * 7 + j]
                          : (short)-1;
  }
  __syncthreads();
  int task0 = t >> 2, l4 = t & 3;
#pragma unroll
  for (int pass = 0; pass < 7; pass++) {
    int task = pass * 64 + task0;          // 0..447
    int nl = task / 56;
    int rem = task - nl * 56;
    int c = rem / 7, j = rem - c * 7;
    int n = n0 + nl;
    int d = idxs[nl][j];
    float s = 0.f;
    if (d >= 0) {
      size_t qo = (((size_t)b * 8 + c) * 256 + n) * 64 + l4 * 16;
      size_t ko = (((size_t)b * 8 + c) * 256 + d) * 64 + l4 * 16;
      const uint4* qh4 = (const uint4*)(qhi + qo);
      const uint4* ql4 = (const uint4*)(qlo + qo);
      const uint4* kh4 = (const uint4*)(khi + ko);
      const uint4* kl4 = (const uint4*)(klo + ko);
#pragma unroll
      for (int g = 0; g < 2; g++) {
        uint4 uqh = qh4[g], uql = ql4[g], ukh = kh4[g], ukl = kl4[g];
        s += dot3_pair(uqh.x, uql.x, ukh.x, ukl.x);
        s += dot3_pair(uqh.y, uql.y, ukh.y, ukl.y);
        s += dot3_pair(uqh.z, uql.z, ukh.z, ukl.z);
        s += dot3_pair(uqh.w, uql.w, ukh.w, ukl.w);
      }
    }
    s += __shfl_xor(s, 1, 64);
    s += __shfl_xor(s, 2, 64);
    if (l4 == 0) {
      float att = 0.f;
      if (d >= 0) {
        float logit = s * 0.125f;
        att = expf(logit - mxb[((size_t)b * 8 + c) * 256 + n]) /
              rzb[((size_t)b * 8 + c) * 256 + n];
      }
      attL[nl][c * 7 + j] = att;
    }
  }
  __syncthreads();
  if (t < 64) {
    int nl = t >> 3, c = t & 7;
    int n = n0 + nl;
    float rs = 0.f;
#pragma unroll
    for (int j = 0; j < 7; j++) rs += attL[nl][c * 7 + j];
    float ri = 1.0f / (rs + 1e-6f);
#pragma unroll
    for (int j = 0; j < 7; j++) {
      float nv = attL[nl][c * 7 + j] * ri;
      nrv[(((size_t)b * 8 + c) * 256 + n) * 7 + j] = nv;
      int d = idxs[nl][j];
      if (d >= 0) atomicAdd(&csL[c][d], nv);   // LDS atomic (nl's may share d)
    }
  }
  __syncthreads();
  for (int i = t; i < 2048; i += 256) {
    float v = ((const float*)csL)[i];
    if (v != 0.f) {
      int c = i >> 8, d = i & 255;
      atomicAdd(&colsum[((size_t)b * 8 + c) * 256 + d], v);
    }
  }
}

// ---------------------------------------------------------------------------
// edge v2 (R6-proven): grid 2048, branchless gather, 28 KB LDS.
// ---------------------------------------------------------------------------
__global__ __launch_bounds__(256, 5) void edge_kernel(
    const int* __restrict__ idx7, const float* __restrict__ nrv,
    const float* __restrict__ colsum, unsigned short* __restrict__ edge) {
  __shared__ unsigned short ncT[256 * 32];   // 16 KB
  __shared__ short idxL[256 * 8];            // 4 KB
  __shared__ float nrvL[256 * 8];            // 8 KB
  int t = threadIdx.x;
  int blk = blockIdx.x;
  int b = blk >> 6, c = (blk >> 3) & 7, mq = blk & 7;
  int m0 = mq * 32;
  for (int i = t; i < 4096; i += 256) ((unsigned int*)ncT)[i] = 0u;
  for (int i = t; i < 2048; i += 256) {
    int r = i >> 3, j = i & 7;
    if (j < 7) {
      idxL[i] = (short)idx7[(size_t)b * 1792 + r * 7 + j];
      nrvL[i] = nrv[((size_t)b * 8 + c) * 1792 + r * 7 + j];
    } else {
      idxL[i] = -1;
      nrvL[i] = 0.f;
    }
  }
  __syncthreads();
  for (int i = t; i < 224; i += 256) {
    int mi = i / 7, j = i - mi * 7;
    int m = m0 + mi;
    int d = idxL[m * 8 + j];
    if (d >= 0) {
      float cs = colsum[((size_t)b * 8 + c) * 256 + d];
      ncT[d * 32 + mi] = f2bf(nrvL[m * 8 + j] / (cs + 1e-6f));
    }
  }
  __syncthreads();
  int wv = t >> 6, l = t & 63;
  int qtr = l >> 4, p = l & 15;
  const unsigned int* ncP = (const unsigned int*)ncT;
  unsigned int* eb = (unsigned int*)(edge + (((size_t)b * 8 + c) * 256) * 256);
#pragma unroll 4
  for (int nn = 0; nn < 16; nn++) {
    int n = nn * 16 + wv * 4 + qtr;
    int4 iv = *(const int4*)(idxL + n * 8);
    float4 w0 = *(const float4*)(nrvL + n * 8);
    float4 w1 = *(const float4*)(nrvL + n * 8 + 4);
    // branchless: d=-1 -> row 255, weight is exactly 0
    unsigned p0 = ncP[(iv.x & 255) * 16 + p];
    unsigned p1 = ncP[((iv.x >> 16) & 255) * 16 + p];
    unsigned p2 = ncP[(iv.y & 255) * 16 + p];
    unsigned p3 = ncP[((iv.y >> 16) & 255) * 16 + p];
    unsigned p4 = ncP[(iv.z & 255) * 16 + p];
    unsigned p5 = ncP[((iv.z >> 16) & 255) * 16 + p];
    unsigned p6 = ncP[(iv.w & 255) * 16 + p];
    float a0 = w0.x * bf2f_lo(p0) + w0.y * bf2f_lo(p1) + w0.z * bf2f_lo(p2)
             + w0.w * bf2f_lo(p3) + w1.x * bf2f_lo(p4) + w1.y * bf2f_lo(p5)
             + w1.z * bf2f_lo(p6);
    float a1 = w0.x * bf2f_hi(p0) + w0.y * bf2f_hi(p1) + w0.z * bf2f_hi(p2)
             + w0.w * bf2f_hi(p3) + w1.x * bf2f_hi(p4) + w1.y * bf2f_hi(p5)
             + w1.z * bf2f_hi(p6);
    unsigned int packo = (unsigned int)f2bf(a0) | ((unsigned int)f2bf(a1) << 16);
    eb[n * 128 + (m0 >> 1) + p] = packo;
  }
}

// ---------------------------------------------------------------------------
// qkx v3: fused xs + qg + kg (row-major). grid 128.
// ---------------------------------------------------------------------------
static __device__ __forceinline__ float selu1(float v) {
  float e = (v > 0.f) ? v : expm1f(v);
  return 1.0f / (1.0f + expf(-e));
}
__global__ __launch_bounds__(256, 1) void qkx_kernel(
    const float* __restrict__ x, const float* __restrict__ gaw,
    const float* __restrict__ gab, int l, float* __restrict__ xs,
    float* __restrict__ qg, float* __restrict__ kg) {
  __shared__ float xsL[64 * 64];
  int t = threadIdx.x;
  int b = blockIdx.x >> 2, nt = blockIdx.x & 3;
  int f = t & 63, part = t >> 6;
  float wq[64], wk[64];
  const float4* Wq4 = (const float4*)(gaw + (size_t)l * 8192 + f * 64);
  const float4* Wk4 = (const float4*)(gaw + (size_t)l * 8192 + (64 + f) * 64);
#pragma unroll
  for (int j = 0; j < 16; j++) {
    float4 aa = Wq4[j];
    wq[4 * j + 0] = aa.x; wq[4 * j + 1] = aa.y; wq[4 * j + 2] = aa.z; wq[4 * j + 3] = aa.w;
    float4 bb = Wk4[j];
    wk[4 * j + 0] = bb.x; wk[4 * j + 1] = bb.y; wk[4 * j + 2] = bb.z; wk[4 * j + 3] = bb.w;
  }
  float bq = gab[l * 128 + f], bk = gab[l * 128 + 64 + f];
  for (int i = t; i < 1024; i += 256) {
    float4 v = ((const float4*)(x + ((size_t)b * 256 + nt * 64) * 64))[i];
    float4 o;
    o.x = selu1(v.x); o.y = selu1(v.y); o.z = selu1(v.z); o.w = selu1(v.w);
    ((float4*)xsL)[i] = o;
    ((float4*)(xs + ((size_t)b * 256 + nt * 64) * 64))[i] = o;
  }
  __syncthreads();
  for (int i = 0; i < 16; i++) {
    int nl = part * 16 + i;
    const float4* xr = (const float4*)(xsL + nl * 64);
    float aq = 0.f, ak = 0.f;
#pragma unroll
    for (int j = 0; j < 16; j++) {
      float4 v = xr[j];
      aq += v.x * wq[4 * j] + v.y * wq[4 * j + 1] + v.z * wq[4 * j + 2] + v.w * wq[4 * j + 3];
      ak += v.x * wk[4 * j] + v.y * wk[4 * j + 1] + v.z * wk[4 * j + 2] + v.w * wk[4 * j + 3];
    }
    int n = nt * 64 + nl;
    qg[((size_t)b * 256 + n) * 64 + f] = aq + bq;
    kg[((size_t)b * 256 + n) * 64 + f] = ak + bk;
  }
}

// ---------------------------------------------------------------------------
// upd v2: ga_attn fused in.
// ---------------------------------------------------------------------------
__global__ __launch_bounds__(256) void upd_kernel(
    const float* __restrict__ qg, const float* __restrict__ kg,
    const unsigned short* __restrict__ edge,
    const float* __restrict__ xs, const float* __restrict__ gaww,
    const float* __restrict__ lipv, int l, float* __restrict__ x) {
  __shared__ float tt[4][8][260];
  __shared__ float ne3[4][256];
  __shared__ float parts[4][4][64];
  __shared__ float dred[32][8];
  __shared__ float dinv[4][8];
  __shared__ float wcL[8];
  __shared__ float lipi;
  __shared__ float qgL[4][64];
  __shared__ float rred[2][4][4];   // [max/sum][row][wave]
  int t = threadIdx.x;
  int b = blockIdx.x >> 6, nq = blockIdx.x & 63;
  int n0 = nq * 4;
  int wave = t >> 6;
  if (t == 0) {
    float s = 0.f;
    float wtmp[8];
    for (int c = 0; c < 8; c++) { wtmp[c] = gaww[l * 8 + c]; s += wtmp[c]; }
    for (int c = 0; c < 8; c++) wcL[c] = wtmp[c] / s;
    lipi = 1.0f / lipv[l];
  }
  {
    int r = t >> 6, f = t & 63;
    qgL[r][f] = qg[((size_t)b * 256 + n0 + r) * 64 + f];
  }
  __syncthreads();
  // ---- inline ga_attn: thread t = column m; 4 rows ----
  float d0 = 0.f, d1 = 0.f, d2 = 0.f, d3 = 0.f;
  {
    const float4* kr = (const float4*)(kg + ((size_t)b * 256 + t) * 64);
#pragma unroll
    for (int j = 0; j < 16; j++) {
      float4 kv = kr[j];
      float4 q0 = ((const float4*)qgL[0])[j];
      float4 q1 = ((const float4*)qgL[1])[j];
      float4 q2 = ((const float4*)qgL[2])[j];
      float4 q3 = ((const float4*)qgL[3])[j];
      d0 += q0.x * kv.x + q0.y * kv.y + q0.z * kv.z + q0.w * kv.w;
      d1 += q1.x * kv.x + q1.y * kv.y + q1.z * kv.z + q1.w * kv.w;
      d2 += q2.x * kv.x + q2.y * kv.y + q2.z * kv.z + q2.w * kv.w;
      d3 += q3.x * kv.x + q3.y * kv.y + q3.z * kv.z + q3.w * kv.w;
    }
  }
  d0 *= 0.125f; d1 *= 0.125f; d2 *= 0.125f; d3 *= 0.125f;
  {
    float m0 = d0, m1 = d1, m2 = d2, m3 = d3;
#pragma unroll
    for (int mm = 1; mm < 64; mm <<= 1) {
      m0 = fmaxf(m0, __shfl_xor(m0, mm, 64));
      m1 = fmaxf(m1, __shfl_xor(m1, mm, 64));
      m2 = fmaxf(m2, __shfl_xor(m2, mm, 64));
      m3 = fmaxf(m3, __shfl_xor(m3, mm, 64));
    }
    if ((t & 63) == 0) {
      rred[0][0][wave] = m0; rred[0][1][wave] = m1;
      rred[0][2][wave] = m2; rred[0][3][wave] = m3;
    }
  }
  __syncthreads();
  {
    float g0 = fmaxf(fmaxf(rred[0][0][0], rred[0][0][1]), fmaxf(rred[0][0][2], rred[0][0][3]));
    float g1 = fmaxf(fmaxf(rred[0][1][0], rred[0][1][1]), fmaxf(rred[0][1][2], rred[0][1][3]));
    float g2 = fmaxf(fmaxf(rred[0][2][0], rred[0][2][1]), fmaxf(rred[0][2][2], rred[0][2][3]));
    float g3 = fmaxf(fmaxf(rred[0][3][0], rred[0][3][1]), fmaxf(rred[0][3][2], rred[0][3][3]));
    d0 = expf(d0 - g0); d1 = expf(d1 - g1); d2 = expf(d2 - g2); d3 = expf(d3 - g3);
    float s0 = d0, s1 = d1, s2 = d2, s3 = d3;
#pragma unroll
    for (int mm = 1; mm < 64; mm <<= 1) {
      s0 += __shfl_xor(s0, mm, 64);
      s1 += __shfl_xor(s1, mm, 64);
      s2 += __shfl_xor(s2, mm, 64);
      s3 += __shfl_xor(s3, mm, 64);
    }
    if ((t & 63) == 0) {
      rred[1][0][wave] = s0; rred[1][1][wave] = s1;
      rred[1][2][wave] = s2; rred[1][3][wave] = s3;
    }
  }
  __syncthreads();
  float av[4];
  {
    float z0 = (rred[1][0][0] + rred[1][0][1]) + (rred[1][0][2] + rred[1][0][3]);
    float z1 = (rred[1][1][0] + rred[1][1][1]) + (rred[1][1][2] + rred[1][1][3]);
    float z2 = (rred[1][2][0] + rred[1][2][1]) + (rred[1][2][2] + rred[1][2][3]);
    float z3 = (rred[1][3][0] + rred[1][3][1]) + (rred[1][3][2] + rred[1][3][3]);
    av[0] = d0 / z0; av[1] = d1 / z1; av[2] = d2 / z2; av[3] = d3 / z3;
  }
  // ---- ne pipeline ----
#pragma unroll
  for (int r = 0; r < 4; r++) {
#pragma unroll
    for (int c = 0; c < 8; c++)
      tt[r][c][t] = av[r] * bf2f(edge[(((size_t)b * 8 + c) * 256 + n0 + r) * 256 + t]);
  }
  __syncthreads();
  {
    int rc = t >> 3, i = t & 7;
    int r = rc >> 3, c = rc & 7;
    float p = 0.f;
#pragma unroll
    for (int kq = 0; kq < 32; kq++) p += tt[r][c][i + 8 * kq];
    dred[rc][i] = p;
  }
  __syncthreads();
  if (t < 32) {
    float s = 0.f;
#pragma unroll
    for (int i = 0; i < 8; i++) s += dred[t][i];
    dinv[t >> 3][t & 7] = 1.0f / (s + 1e-6f);
  }
  __syncthreads();
#pragma unroll
  for (int r = 0; r < 4; r++) {
    float s = 0.f;
#pragma unroll
    for (int c = 0; c < 8; c++) s += wcL[c] * tt[r][c][t] * dinv[r][c];
    ne3[r][t] = s;
  }
  __syncthreads();
  {
    int f = t & 63, part = t >> 6;
    float a0 = 0.f, a1 = 0.f, a2 = 0.f, a3 = 0.f;
    for (int mm = 0; mm < 64; mm++) {
      int m = part * 64 + mm;
      float xv = xs[((size_t)b * 256 + m) * 64 + f];
      a0 += ne3[0][m] * xv;
      a1 += ne3[1][m] * xv;
      a2 += ne3[2][m] * xv;
      a3 += ne3[3][m] * xv;
    }
    parts[0][part][f] = a0;
    parts[1][part][f] = a1;
    parts[2][part][f] = a2;
    parts[3][part][f] = a3;
  }
  __syncthreads();
  {
    int r = t >> 6, f = t & 63;
    float dx = parts[r][0][f] + parts[r][1][f] + parts[r][2][f] + parts[r][3][f];
    x[((size_t)b * 256 + n0 + r) * 64 + f] += dx * lipi;
  }
}

// ---------------------------------------------------------------------------
extern "C" void kernel_launch(void* const* d_in, const int* in_sizes, int n_in,
                              void* d_out, int out_size, void* d_ws, size_t ws_size,
                              hipStream_t stream) {
  (void)in_sizes; (void)n_in; (void)out_size; (void)ws_size;
  const float* fused = (const float*)d_in[0];
  const float* w1 = (const float*)d_in[1];
  const float* b1 = (const float*)d_in[2];
  const float* w2 = (const float*)d_in[3];
  const float* b2 = (const float*)d_in[4];
  const float* eqk = (const float*)d_in[5];
  const float* gaw = (const float*)d_in[6];
  const float* gab = (const float*)d_in[7];
  const float* gaww = (const float*)d_in[8];
  float* x = (float*)d_out;  // x lives in d_out (B,ND,NF)=(32,256,64); fully overwritten.
  char* ws = (char*)d_ws;
  size_t off = 0;
  auto alloc = [&](size_t bytes) -> char* {
    char* p = ws + off;
    off += (bytes + 1023) & ~(size_t)1023;
    return p;
  };
  float* invsig1 = (float*)alloc(64 * 4);
  float* invsig2 = (float*)alloc(64 * 4);
  float* lipv = (float*)alloc(2 * 4);
  unsigned short* qhi = (unsigned short*)alloc((size_t)32 * 8 * 256 * 64 * 2);
  unsigned short* qlo = (unsigned short*)alloc((size_t)32 * 8 * 256 * 64 * 2);
  unsigned short* khi = (unsigned short*)alloc((size_t)32 * 8 * 256 * 64 * 2);
  unsigned short* klo = (unsigned short*)alloc((size_t)32 * 8 * 256 * 64 * 2);
  // seP (4 partials, 33.5 MB) aliases edge (33.5 MB): seP dead after topsel.
  char* sep_edge = alloc((size_t)4 * 32 * 256 * 256 * 4);
  float* seP = (float*)sep_edge;
  unsigned short* edge = (unsigned short*)sep_edge;
  float* mxb = (float*)alloc((size_t)65536 * 4);
  float* rzb = (float*)alloc((size_t)65536 * 4);
  int* idx7 = (int*)alloc((size_t)8192 * 7 * 4);
  float* nrv = (float*)alloc((size_t)65536 * 7 * 4);
  float* colsum = (float*)alloc((size_t)65536 * 4);
  float* xs = (float*)alloc((size_t)524288 * 4);
  float* qg = (float*)alloc((size_t)524288 * 4);
  float* kg = (float*)alloc((size_t)524288 * 4);

  speclip_kernel<<<130, 256, 0, stream>>>(w1, w2, gaw, invsig1, invsig2, lipv);
  hconv_kernel<<<512, 256, 0, stream>>>(fused, w1, b1, invsig1, w2, b2, invsig2, x);
  qk_kernel<<<512, 256, 0, stream>>>(x, eqk, qhi, qlo, khi, klo);
  attn_kernel<<<512, 512, 0, stream>>>(qhi, qlo, khi, klo, seP, mxb, rzb);
  topsel_kernel<<<128, 256, 0, stream>>>(seP, idx7, colsum);
  nr_kernel<<<1024, 256, 0, stream>>>(qhi, qlo, khi, klo, mxb, rzb, idx7, nrv, colsum);
  edge_kernel<<<2048, 256, 0, stream>>>(idx7, nrv, colsum, edge);
  for (int l = 0; l < 2; l++) {
    qkx_kernel<<<128, 256, 0, stream>>>(x, gaw, gab, l, xs, qg, kg);
    upd_kernel<<<2048, 256, 0, stream>>>(qg, kg, edge, xs, gaww, lipv, l, x);
  }
}